// Round 2
// baseline (3104.075 us; speedup 1.0000x reference)
//
#include <hip/hip_runtime.h>
#include <math.h>

#define NTY 5
#define NET 10
#define NTOT 307000
#define ETOT 6800000
#define GDIM 1024
#define PDIM 768

// ---- compile-time problem tables (host) ----
static const int kNS[NET]  = {5000,5000,5000,2000,2000,50000,100000,150000,50000,100000};
static const int kND[NET]  = {50000,100000,150000,50000,100000,5000,5000,5000,2000,2000};
static const int kEC[NET]  = {500000,1000000,1000000,300000,600000,500000,1000000,1000000,300000,600000};
static const int kSRCT[NET]= {0,0,0,4,4,1,2,3,1,2};
static const int kDSTT[NET]= {1,2,3,1,2,0,0,0,8/0+1,4};  // placeholder fixed below
static const int kNT[NTY]  = {5000,50000,100000,150000,2000};
static const int kTOFF[NTY]= {0,5000,55000,155000,305000};
static const int kEB[NET+1]= {0,500000,1500000,2500000,2800000,3400000,3900000,4900000,5900000,6200000,6800000};
static const int kRB[NET+1]= {0,50000,150000,300000,350000,450000,455000,460000,465000,467000,469000};
static const int kBB[NET+1]= {0,49,147,294,343,441,446,451,456,458,460};
static const int kSB[NET+1]= {0,5000,10000,15000,17000,19000,69000,169000,319000,369000,469000};
static const int kGB[NET+1]= {0,79,158,237,269,301,1083,2646,4990,5772,7335};
static const int kDSTT2[NET]= {1,2,3,1,2,0,0,0,4,4};

// ---- device tables ----
__device__ const int gOB[NET]   = {0,50001,150002,300003,350004,450005,455006,460007,465008,467009};
__device__ const int gEB[NET]   = {0,500000,1500000,2500000,2800000,3400000,3900000,4900000,5900000,6200000};
__device__ const int gSB[NET]   = {0,5000,10000,15000,17000,19000,69000,169000,319000,369000};
__device__ const int gTOFF[NTY] = {0,5000,55000,155000,305000};
__device__ const int gNIN[NTY]  = {3,2,2,1,2};
__device__ const int gINET[NTY][3] = {{5,6,7},{0,3,0},{1,4,0},{2,0,0},{8,9,0}};

struct EdgeTab {
  const int* ei[NET];
  int ebase[NET+1];
  int obase[NET];
  int rbase[NET+1];
};
struct ScanTab {
  int bbase[NET+1];
  int cbase[NET];
  int obase[NET];
  int pbase[NET];
  int nd[NET];
  int ec[NET];
};
struct BiasTab { int dstt[NET]; };
struct PoolTab { const int* batch[NTY]; const float* x[NTY]; int nt[NTY]; };
struct GemmTab {
  const float* X[NET];
  const float* Wsrc;
  const float* asrc;
  float* hs;
  float* ssrc;
  int K;
};
struct AggTab {
  const int* offs;
  const int* csr;
  const float* hs;
  const float* ssrc;
  const float* xin[NTY];
  const float* wv;
  const float* bsum;
  float* xout;
  int K;
};

// ---------------- CSR build ----------------
__global__ __launch_bounds__(256) void k_hist(EdgeTab t, int* __restrict__ counts) {
  int gid = blockIdx.x*256 + threadIdx.x;
  if (gid >= t.ebase[NET]) return;
  int et = 0;
  #pragma unroll
  for (int i=0;i<NET;i++) if (gid >= t.ebase[i+1]) et = i+1;
  int e = gid - t.ebase[et];
  int E = t.ebase[et+1]-t.ebase[et];
  int dst = t.ei[et][E + e];
  atomicAdd(&counts[t.rbase[et] + dst], 1);
}

__global__ __launch_bounds__(256) void k_scan1(ScanTab t, const int* __restrict__ counts,
                                               int* __restrict__ offs, int* __restrict__ partials) {
  __shared__ int sd[256];
  int b = blockIdx.x;
  int et = 0;
  #pragma unroll
  for (int i=0;i<NET;i++) if (b >= t.bbase[i+1]) et = i+1;
  int lb = b - t.bbase[et];
  int n = t.nd[et];
  const int* cin = counts + t.cbase[et];
  int* oo = offs + t.obase[et];
  int tid = threadIdx.x;
  int base = lb*1024 + tid*4;
  int v0 = (base+0<n)?cin[base+0]:0;
  int v1 = (base+1<n)?cin[base+1]:0;
  int v2 = (base+2<n)?cin[base+2]:0;
  int v3 = (base+3<n)?cin[base+3]:0;
  int tsum = v0+v1+v2+v3;
  sd[tid]=tsum; __syncthreads();
  for (int off=1; off<256; off<<=1) {
    int x = (tid>=off)? sd[tid-off] : 0;
    __syncthreads();
    sd[tid] += x;
    __syncthreads();
  }
  int run = sd[tid]-tsum;
  if (tid==255) partials[t.pbase[et]+lb]=sd[255];
  if (base+0<n){ oo[base+0]=run; run+=v0; }
  if (base+1<n){ oo[base+1]=run; run+=v1; }
  if (base+2<n){ oo[base+2]=run; run+=v2; }
  if (base+3<n){ oo[base+3]=run; }
}

__global__ __launch_bounds__(256) void k_scan2(ScanTab t, int* __restrict__ partials) {
  __shared__ int sd[256];
  int et = blockIdx.x;
  int nb = t.bbase[et+1]-t.bbase[et];
  int tid = threadIdx.x;
  int v = (tid<nb)? partials[t.pbase[et]+tid] : 0;
  sd[tid]=v; __syncthreads();
  for (int off=1; off<256; off<<=1) {
    int x=(tid>=off)?sd[tid-off]:0;
    __syncthreads();
    sd[tid]+=x;
    __syncthreads();
  }
  if (tid<nb) partials[t.pbase[et]+tid] = sd[tid]-v;
}

__global__ __launch_bounds__(256) void k_scan3(ScanTab t, int* __restrict__ offs,
                                               const int* __restrict__ partials) {
  int b = blockIdx.x;
  int et=0;
  #pragma unroll
  for (int i=0;i<NET;i++) if (b>=t.bbase[i+1]) et=i+1;
  int lb = b - t.bbase[et];
  int n = t.nd[et];
  int* oo = offs + t.obase[et];
  int add = partials[t.pbase[et]+lb];
  int tid = threadIdx.x;
  int base = lb*1024 + tid*4;
  #pragma unroll
  for (int j=0;j<4;j++) if (base+j<n) oo[base+j]+=add;
  if (lb==0 && tid==0) oo[n] = t.ec[et];
}

__global__ __launch_bounds__(256) void k_scatter(EdgeTab t, int* __restrict__ cursor, int* __restrict__ csr) {
  int gid = blockIdx.x*256 + threadIdx.x;
  if (gid >= t.ebase[NET]) return;
  int et=0;
  #pragma unroll
  for (int i=0;i<NET;i++) if (gid>=t.ebase[i+1]) et=i+1;
  int e = gid - t.ebase[et];
  int E = t.ebase[et+1]-t.ebase[et];
  int src = t.ei[et][e];
  int dst = t.ei[et][E+e];
  int pos = atomicAdd(&cursor[t.obase[et]+dst], 1);
  csr[t.ebase[et] + pos] = src;
}

// ---------------- per-layer ----------------
__global__ void k_bias(const float* __restrict__ b, BiasTab t, float* __restrict__ bsum) {
  int tid = threadIdx.x;            // 320 threads
  int ty = tid>>6, c = tid&63;
  float s = 0.f;
  #pragma unroll
  for (int i=0;i<NET;i++) if (t.dstt[i]==ty) s += b[i*64+c];
  bsum[tid]=s;
}

__global__ void k_wdst(const float* __restrict__ Wd, const float* __restrict__ ad,
                       float* __restrict__ wv, int K) {
  int et = blockIdx.x; int k = threadIdx.x;
  if (k>=K) return;
  const float* W = Wd + (long)et*K*64;
  const float* a = ad + et*64;
  float s=0.f;
  #pragma unroll 8
  for (int c=0;c<64;c++) s += W[k*64+c]*a[c];
  wv[et*256+k]=s;
}

// fused GEMM over all 10 edge types: hs[SB[et]+r] = X_et[r] @ Wsrc[et], score = hs @ asrc[et]
__global__ __launch_bounds__(256) void k_gemm_all(GemmTab t) {
  __shared__ float sX[64][68];
  __shared__ float sW[64][64];
  int b = blockIdx.x;
  int et = 0;
  // host-side kGB mirrored here as immediate constants
  const int GB1=79,GB2=158,GB3=237,GB4=269,GB5=301,GB6=1083,GB7=2646,GB8=4990,GB9=5772;
  et = (b>=GB1)+(b>=GB2)+(b>=GB3)+(b>=GB4)+(b>=GB5)+(b>=GB6)+(b>=GB7)+(b>=GB8)+(b>=GB9);
  const int GBb[NET] = {0,GB1,GB2,GB3,GB4,GB5,GB6,GB7,GB8,GB9};
  const int NSa[NET] = {5000,5000,5000,2000,2000,50000,100000,150000,50000,100000};
  int lb = b - GBb[et];
  int Ns = NSa[et];
  int K = t.K;
  const float* X = t.X[et];
  const float* W = t.Wsrc + (long)et*K*64;
  const float* avec = t.asrc + et*64;
  int sbase = gSB[et];
  float* HS = t.hs + (long)sbase*64;
  float* score = t.ssrc + sbase;

  int tid = threadIdx.x;
  int row0 = lb*64;
  int tr = tid>>4, tc = tid&15;
  float acc[4][4]={};
  for (int k0=0;k0<K;k0+=64){
    #pragma unroll
    for (int p=0;p<4;p++){
      int r = (tid>>4) + 16*p;
      int c = (tid&15)*4;
      int gr = row0 + r;
      float4 xv = make_float4(0.f,0.f,0.f,0.f);
      if (gr < Ns) xv = *(const float4*)(X + (long)gr*K + k0 + c);
      sX[r][c]=xv.x; sX[r][c+1]=xv.y; sX[r][c+2]=xv.z; sX[r][c+3]=xv.w;
      float4 wv4 = *(const float4*)(W + (long)(k0+r)*64 + c);
      *(float4*)&sW[r][c] = wv4;
    }
    __syncthreads();
    #pragma unroll 8
    for (int k=0;k<64;k++){
      float a0=sX[tr*4+0][k],a1=sX[tr*4+1][k],a2=sX[tr*4+2][k],a3=sX[tr*4+3][k];
      float4 b4 = *(const float4*)&sW[k][tc*4];
      acc[0][0]+=a0*b4.x; acc[0][1]+=a0*b4.y; acc[0][2]+=a0*b4.z; acc[0][3]+=a0*b4.w;
      acc[1][0]+=a1*b4.x; acc[1][1]+=a1*b4.y; acc[1][2]+=a1*b4.z; acc[1][3]+=a1*b4.w;
      acc[2][0]+=a2*b4.x; acc[2][1]+=a2*b4.y; acc[2][2]+=a2*b4.z; acc[2][3]+=a2*b4.w;
      acc[3][0]+=a3*b4.x; acc[3][1]+=a3*b4.y; acc[3][2]+=a3*b4.z; acc[3][3]+=a3*b4.w;
    }
    __syncthreads();
  }
  float a4[4];
  #pragma unroll
  for (int j=0;j<4;j++) a4[j]=avec[tc*4+j];
  #pragma unroll
  for (int i=0;i<4;i++){
    int r = row0 + tr*4 + i;
    if (r < Ns){
      float4 o; o.x=acc[i][0]; o.y=acc[i][1]; o.z=acc[i][2]; o.w=acc[i][3];
      *(float4*)(HS + (long)r*64 + tc*4) = o;
    }
    float sc = acc[i][0]*a4[0]+acc[i][1]*a4[1]+acc[i][2]*a4[2]+acc[i][3]*a4[3];
    #pragma unroll
    for (int off=1;off<16;off<<=1) sc += __shfl_xor(sc, off);
    if (tc==0 && r<Ns) score[r]=sc;
  }
}

// fused aggregation: one wave per dst node; loops incoming edge types;
// computes sdst dot in-block; applies bias + relu; writes final layer output.
__global__ __launch_bounds__(256) void k_agg_all(AggTab t) {
  int node = blockIdx.x*4 + (threadIdx.x>>6);
  int lane = threadIdx.x & 63;
  if (node >= NTOT) return;
  int ty = (node>=5000)+(node>=55000)+(node>=155000)+(node>=305000);
  int r = node - gTOFF[ty];
  int K = t.K;
  const float* xrow = t.xin[ty] + (long)r*K;
  float outacc = 0.f;
  int ne = gNIN[ty];
  for (int ii=0; ii<ne; ii++) {
    int et = gINET[ty][ii];
    // dst-score dot: (x_d @ Wdst) @ adst  ==  x_d @ (Wdst @ adst) = x_d . wv
    const float* wvv = t.wv + et*256;
    float sd = 0.f;
    for (int k=lane;k<K;k+=64) sd += xrow[k]*wvv[k];
    #pragma unroll
    for (int off=32;off;off>>=1) sd += __shfl_xor(sd,off);
    int ob = gOB[et];
    int beg = t.offs[ob + r];
    int end = t.offs[ob + r + 1];
    if (beg < end) {
      const int* cs = t.csr + gEB[et];
      int sb = gSB[et];
      const float* ss = t.ssrc + sb;
      const float* hsb = t.hs + (long)sb*64;
      float m = -3.0e38f;
      for (int e=beg+lane; e<end; e+=64) {
        float l = ss[cs[e]] + sd;
        l = (l>0.f)? l : 0.2f*l;
        m = fmaxf(m,l);
      }
      #pragma unroll
      for (int off=32;off;off>>=1) m = fmaxf(m,__shfl_xor(m,off));
      float den=0.f, acc=0.f;
      for (int e=beg;e<end;e++){
        int s = cs[e];
        float l = ss[s]+sd; l=(l>0.f)?l:0.2f*l;
        float ex = __expf(l-m);
        den += ex;
        acc += ex*hsb[(long)s*64+lane];
      }
      outacc += acc/(den+1e-16f);
    }
  }
  float o = outacc + t.bsum[ty*64+lane];
  t.xout[(long)node*64+lane] = fmaxf(o,0.f);
}

// ---------------- pooling + head ----------------
__global__ __launch_bounds__(64) void k_pool(PoolTab t, float* __restrict__ pooled) {
  int g = blockIdx.x; int ty = blockIdx.y; int lane = threadIdx.x;
  const int* batch = t.batch[ty];
  int n = t.nt[ty];
  int lo=0, hi=0;
  if (lane==0){
    int a=0,b2=n;
    while(a<b2){int mm=(a+b2)>>1; if (batch[mm]<g) a=mm+1; else b2=mm;}
    lo=a;
    a=lo; b2=n;
    while(a<b2){int mm=(a+b2)>>1; if (batch[mm]<g+1) a=mm+1; else b2=mm;}
    hi=a;
  }
  lo=__shfl(lo,0); hi=__shfl(hi,0);
  const float* x = t.x[ty];
  float acc=0.f;
  for (int i=lo;i<hi;i++) acc += x[(long)i*64+lane];
  int cnt = hi-lo;
  pooled[(long)g*320 + ty*64 + lane] = acc / (float)(cnt>0?cnt:1);
}

__global__ __launch_bounds__(256) void k_final(
    const float* __restrict__ pooled, const float* __restrict__ post,
    const float* __restrict__ Wlin, const float* __restrict__ blin,
    float* __restrict__ out)
{
  int w = (blockIdx.x*256+threadIdx.x)>>6;
  int lane = threadIdx.x&63;
  if (w>=GDIM) return;
  float a0=0.f,a1=0.f;
  for (int k=lane;k<320+PDIM;k+=64){
    float v = (k<320) ? pooled[(long)w*320+k] : post[(long)w*PDIM + (k-320)];
    a0 += v*Wlin[k*2];
    a1 += v*Wlin[k*2+1];
  }
  #pragma unroll
  for (int off=32;off;off>>=1){ a0+=__shfl_xor(a0,off); a1+=__shfl_xor(a1,off); }
  if (lane==0){
    float z0=a0+blin[0], z1=a1+blin[1];
    z0=fmaxf(z0,0.f); z1=fmaxf(z1,0.f);
    float mm=fmaxf(z0,z1);
    float e0=__expf(z0-mm), e1=__expf(z1-mm);
    float inv = 1.f/(e0+e1);
    out[w*2+0]=e0*inv; out[w*2+1]=e1*inv;
  }
}

extern "C" void kernel_launch(void* const* d_in, const int* in_sizes, int n_in,
                              void* d_out, int out_size, void* d_ws, size_t ws_size,
                              hipStream_t stream) {
  (void)in_sizes; (void)n_in; (void)out_size; (void)ws_size; (void)kDSTT;
  char* ws = (char*)d_ws;
  size_t off = 0;
  auto A = [&](size_t nbytes){ size_t o=off; off=(off+nbytes+255)&~((size_t)255); return o; };
  size_t xbuf1_o = A((size_t)NTOT*64*4);        // 78.6 MB
  size_t xbuf2_o = A((size_t)NTOT*64*4);        // 78.6 MB
  size_t hs_o    = A((size_t)469000*64*4);      // 120 MB
  size_t csr_o   = A((size_t)ETOT*4);           // 27.2 MB
  size_t offs_o  = A((size_t)469010*4);
  size_t cur_o   = A((size_t)469010*4);
  size_t cnt_o   = A((size_t)469000*4);
  size_t ssrc_o  = A((size_t)469000*4);
  size_t pool_o  = A((size_t)GDIM*320*4);
  size_t wv_o    = A((size_t)NET*256*4);
  size_t bsum_o  = A((size_t)320*4);
  size_t part_o  = A((size_t)460*4);

  float* xbuf1 = (float*)(ws + xbuf1_o);
  float* xbuf2 = (float*)(ws + xbuf2_o);
  float* hsB   = (float*)(ws + hs_o);
  int*   csr   = (int*)(ws + csr_o);
  int*   offs  = (int*)(ws + offs_o);
  int*   cur   = (int*)(ws + cur_o);
  int*   cnts  = (int*)(ws + cnt_o);
  float* ssrcB = (float*)(ws + ssrc_o);
  float* pooled= (float*)(ws + pool_o);
  float* wv    = (float*)(ws + wv_o);
  float* bsum  = (float*)(ws + bsum_o);
  int*   parts = (int*)(ws + part_o);

  int kOB[NET];
  for (int i=0;i<NET;i++) kOB[i] = kRB[i] + i;

  // ---- build CSR (edge structure is layer-invariant) ----
  EdgeTab et;
  for (int i=0;i<NET;i++) et.ei[i] = (const int*)d_in[6+i];
  for (int i=0;i<=NET;i++) { et.ebase[i]=kEB[i]; et.rbase[i]=kRB[i]; }
  for (int i=0;i<NET;i++) et.obase[i]=kOB[i];

  ScanTab st;
  for (int i=0;i<=NET;i++) st.bbase[i]=kBB[i];
  for (int i=0;i<NET;i++) { st.cbase[i]=kRB[i]; st.obase[i]=kOB[i]; st.pbase[i]=kBB[i]; st.nd[i]=kND[i]; st.ec[i]=kEC[i]; }

  hipMemsetAsync(cnts, 0, (size_t)469000*4, stream);
  int egrid = (ETOT+255)/256;
  k_hist<<<egrid,256,0,stream>>>(et, cnts);
  k_scan1<<<kBB[NET],256,0,stream>>>(st, cnts, offs, parts);
  k_scan2<<<NET,256,0,stream>>>(st, parts);
  k_scan3<<<kBB[NET],256,0,stream>>>(st, offs, parts);
  hipMemcpyAsync(cur, offs, (size_t)469010*4, hipMemcpyDeviceToDevice, stream);
  k_scatter<<<egrid,256,0,stream>>>(et, cur, csr);

  BiasTab bt; for (int i=0;i<NET;i++) bt.dstt[i]=kDSTT2[i];

  // ---- two GAT layers ----
  for (int l=0;l<2;l++){
    const float* Wsrc = (const float*)d_in[21+5*l];
    const float* Wdst = (const float*)d_in[22+5*l];
    const float* asrc = (const float*)d_in[23+5*l];
    const float* adst = (const float*)d_in[24+5*l];
    const float* bb   = (const float*)d_in[25+5*l];
    int K = l ? 64 : 256;
    const float* xin[NTY];
    float* xout = l ? xbuf2 : xbuf1;
    for (int t=0;t<NTY;t++)
      xin[t] = l ? (const float*)(xbuf1 + (long)kTOFF[t]*64) : (const float*)d_in[t];

    k_bias<<<1,320,0,stream>>>(bb, bt, bsum);
    k_wdst<<<NET,K,0,stream>>>(Wdst, adst, wv, K);

    GemmTab gt;
    for (int e=0;e<NET;e++) gt.X[e] = xin[kSRCT[e]];
    gt.Wsrc = Wsrc; gt.asrc = asrc; gt.hs = hsB; gt.ssrc = ssrcB; gt.K = K;
    k_gemm_all<<<kGB[NET],256,0,stream>>>(gt);

    AggTab at;
    at.offs = offs; at.csr = csr; at.hs = hsB; at.ssrc = ssrcB;
    for (int t=0;t<NTY;t++) at.xin[t] = xin[t];
    at.wv = wv; at.bsum = bsum; at.xout = xout; at.K = K;
    k_agg_all<<<(NTOT+3)/4,256,0,stream>>>(at);
  }

  // ---- pooling + head ----
  PoolTab pt;
  for (int t=0;t<NTY;t++){
    pt.batch[t] = (const int*)d_in[16+t];
    pt.x[t] = (const float*)(xbuf2 + (long)kTOFF[t]*64);
    pt.nt[t] = kNT[t];
  }
  dim3 pgrid(GDIM, NTY);
  k_pool<<<pgrid,64,0,stream>>>(pt, pooled);

  k_final<<<GDIM/4,256,0,stream>>>(pooled, (const float*)d_in[5],
                                   (const float*)d_in[31], (const float*)d_in[32],
                                   (float*)d_out);
}

// Round 3
// 2092.271 us; speedup vs baseline: 1.4836x; 1.4836x over previous
//
#include <hip/hip_runtime.h>
#include <math.h>

#define NTY 5
#define NET 10
#define NTOT 307000
#define ETOT 6800000
#define GDIM 1024
#define PDIM 768

// ---- compile-time problem tables (host) ----
static const int kNS[NET]  = {5000,5000,5000,2000,2000,50000,100000,150000,50000,100000};
static const int kND[NET]  = {50000,100000,150000,50000,100000,5000,5000,5000,2000,2000};
static const int kEC[NET]  = {500000,1000000,1000000,300000,600000,500000,1000000,1000000,300000,600000};
static const int kSRCT[NET]= {0,0,0,4,4,1,2,3,1,2};
static const int kDSTT2[NET]= {1,2,3,1,2,0,0,0,4,4};
static const int kNT[NTY]  = {5000,50000,100000,150000,2000};
static const int kTOFF[NTY]= {0,5000,55000,155000,305000};
static const int kEB[NET+1]= {0,500000,1500000,2500000,2800000,3400000,3900000,4900000,5900000,6200000,6800000};
static const int kRB[NET+1]= {0,50000,150000,300000,350000,450000,455000,460000,465000,467000,469000};
static const int kBB[NET+1]= {0,49,147,294,343,441,446,451,456,458,460};
static const int kGB[NET+1]= {0,79,158,237,269,301,1083,2646,4990,5772,7335};

// ---- device tables ----
__device__ const int gOB[NET]   = {0,50001,150002,300003,350004,450005,455006,460007,465008,467009};
__device__ const int gEB[NET]   = {0,500000,1500000,2500000,2800000,3400000,3900000,4900000,5900000,6200000};
__device__ const int gSB[NET]   = {0,5000,10000,15000,17000,19000,69000,169000,319000,369000};
__device__ const int gRB[NET]   = {0,50000,150000,300000,350000,450000,455000,460000,465000,467000};
__device__ const int gTOFF[NTY] = {0,5000,55000,155000,305000};
__device__ const int gNIN[NTY]  = {3,2,2,1,2};
__device__ const int gINET[NTY][3] = {{5,6,7},{0,3,0},{1,4,0},{2,0,0},{8,9,0}};
// dst-dot assignments: which gemm et computes sdst for which target ets
__device__ const int gNJ[NET]   = {3,0,0,2,0,2,2,1,0,0};
__device__ const int gTG[NET][3]= {{5,6,7},{0,0,0},{0,0,0},{8,9,0},{0,0,0},{0,3,0},{1,4,0},{2,0,0},{0,0,0},{0,0,0}};

struct EdgeTab {
  const int* ei[NET];
  int ebase[NET+1];
  int obase[NET];
  int rbase[NET+1];
};
struct ScanTab {
  int bbase[NET+1];
  int cbase[NET];
  int obase[NET];
  int pbase[NET];
  int nd[NET];
  int ec[NET];
};
struct BiasTab { int dstt[NET]; };
struct PoolTab { const int* batch[NTY]; const float* x[NTY]; int nt[NTY]; };
struct GemmTab {
  const float* X[NET];
  const float* Wsrc;
  const float* asrc;
  const float* wv;
  float* hs;
  float* ssrc;
  float* sdst;
  int K;
};
struct AggTab {
  const int* offs;
  const int* csr;
  const float* hs;
  const float* ssrc;
  const float* sdst;
  const float* bsum;
  float* xout;
};

// ---------------- CSR build ----------------
__global__ __launch_bounds__(256) void k_hist(EdgeTab t, int* __restrict__ counts) {
  int gid = blockIdx.x*256 + threadIdx.x;
  if (gid >= t.ebase[NET]) return;
  int et = 0;
  #pragma unroll
  for (int i=0;i<NET;i++) if (gid >= t.ebase[i+1]) et = i+1;
  int e = gid - t.ebase[et];
  int E = t.ebase[et+1]-t.ebase[et];
  int dst = t.ei[et][E + e];
  atomicAdd(&counts[t.rbase[et] + dst], 1);
}

__global__ __launch_bounds__(256) void k_scan1(ScanTab t, const int* __restrict__ counts,
                                               int* __restrict__ offs, int* __restrict__ partials) {
  __shared__ int sd[256];
  int b = blockIdx.x;
  int et = 0;
  #pragma unroll
  for (int i=0;i<NET;i++) if (b >= t.bbase[i+1]) et = i+1;
  int lb = b - t.bbase[et];
  int n = t.nd[et];
  const int* cin = counts + t.cbase[et];
  int* oo = offs + t.obase[et];
  int tid = threadIdx.x;
  int base = lb*1024 + tid*4;
  int v0 = (base+0<n)?cin[base+0]:0;
  int v1 = (base+1<n)?cin[base+1]:0;
  int v2 = (base+2<n)?cin[base+2]:0;
  int v3 = (base+3<n)?cin[base+3]:0;
  int tsum = v0+v1+v2+v3;
  sd[tid]=tsum; __syncthreads();
  for (int off=1; off<256; off<<=1) {
    int x = (tid>=off)? sd[tid-off] : 0;
    __syncthreads();
    sd[tid] += x;
    __syncthreads();
  }
  int run = sd[tid]-tsum;
  if (tid==255) partials[t.pbase[et]+lb]=sd[255];
  if (base+0<n){ oo[base+0]=run; run+=v0; }
  if (base+1<n){ oo[base+1]=run; run+=v1; }
  if (base+2<n){ oo[base+2]=run; run+=v2; }
  if (base+3<n){ oo[base+3]=run; }
}

__global__ __launch_bounds__(256) void k_scan2(ScanTab t, int* __restrict__ partials) {
  __shared__ int sd[256];
  int et = blockIdx.x;
  int nb = t.bbase[et+1]-t.bbase[et];
  int tid = threadIdx.x;
  int v = (tid<nb)? partials[t.pbase[et]+tid] : 0;
  sd[tid]=v; __syncthreads();
  for (int off=1; off<256; off<<=1) {
    int x=(tid>=off)?sd[tid-off]:0;
    __syncthreads();
    sd[tid]+=x;
    __syncthreads();
  }
  if (tid<nb) partials[t.pbase[et]+tid] = sd[tid]-v;
}

__global__ __launch_bounds__(256) void k_scan3(ScanTab t, int* __restrict__ offs,
                                               const int* __restrict__ partials) {
  int b = blockIdx.x;
  int et=0;
  #pragma unroll
  for (int i=0;i<NET;i++) if (b>=t.bbase[i+1]) et=i+1;
  int lb = b - t.bbase[et];
  int n = t.nd[et];
  int* oo = offs + t.obase[et];
  int add = partials[t.pbase[et]+lb];
  int tid = threadIdx.x;
  int base = lb*1024 + tid*4;
  #pragma unroll
  for (int j=0;j<4;j++) if (base+j<n) oo[base+j]+=add;
  if (lb==0 && tid==0) oo[n] = t.ec[et];
}

__global__ __launch_bounds__(256) void k_scatter(EdgeTab t, int* __restrict__ cursor, int* __restrict__ csr) {
  int gid = blockIdx.x*256 + threadIdx.x;
  if (gid >= t.ebase[NET]) return;
  int et=0;
  #pragma unroll
  for (int i=0;i<NET;i++) if (gid>=t.ebase[i+1]) et=i+1;
  int e = gid - t.ebase[et];
  int E = t.ebase[et+1]-t.ebase[et];
  int src = t.ei[et][e];
  int dst = t.ei[et][E+e];
  int pos = atomicAdd(&cursor[t.obase[et]+dst], 1);
  csr[t.ebase[et] + pos] = src;
}

// ---------------- per-layer ----------------
__global__ void k_bias(const float* __restrict__ b, BiasTab t, float* __restrict__ bsum) {
  int tid = threadIdx.x;            // 320 threads
  int ty = tid>>6, c = tid&63;
  float s = 0.f;
  #pragma unroll
  for (int i=0;i<NET;i++) if (t.dstt[i]==ty) s += b[i*64+c];
  bsum[tid]=s;
}

__global__ void k_wdst(const float* __restrict__ Wd, const float* __restrict__ ad,
                       float* __restrict__ wv, int K) {
  int et = blockIdx.x; int k = threadIdx.x;
  if (k>=K) return;
  const float* W = Wd + (long)et*K*64;
  const float* a = ad + et*64;
  float s=0.f;
  #pragma unroll 8
  for (int c=0;c<64;c++) s += W[k*64+c]*a[c];
  wv[et*256+k]=s;
}

// fused GEMM over all 10 edge types:
//   hs[SB[et]+r] = X_et[r] @ Wsrc[et];  ssrc = hs @ asrc[et]
//   + designated blocks also compute sdst[tg] = X_row . wv[tg] from the staged LDS tile
__global__ __launch_bounds__(256) void k_gemm_all(GemmTab t) {
  __shared__ float sX[64][68];
  __shared__ float sW[64][64];
  __shared__ float sdd[3][64][4];
  int b = blockIdx.x;
  const int GB1=79,GB2=158,GB3=237,GB4=269,GB5=301,GB6=1083,GB7=2646,GB8=4990,GB9=5772;
  int et = (b>=GB1)+(b>=GB2)+(b>=GB3)+(b>=GB4)+(b>=GB5)+(b>=GB6)+(b>=GB7)+(b>=GB8)+(b>=GB9);
  const int GBb[NET] = {0,GB1,GB2,GB3,GB4,GB5,GB6,GB7,GB8,GB9};
  const int NSa[NET] = {5000,5000,5000,2000,2000,50000,100000,150000,50000,100000};
  int lb = b - GBb[et];
  int Ns = NSa[et];
  int K = t.K;
  const float* X = t.X[et];
  const float* W = t.Wsrc + (long)et*K*64;
  const float* avec = t.asrc + et*64;
  int sbase = gSB[et];
  float* HS = t.hs + (long)sbase*64;
  float* score = t.ssrc + sbase;

  int nj = gNJ[et];
  const float* wvA = t.wv + gTG[et][0]*256;
  const float* wvB = t.wv + gTG[et][1]*256;
  const float* wvC = t.wv + gTG[et][2]*256;

  int tid = threadIdx.x;
  int row0 = lb*64;
  int tr = tid>>4, tc = tid&15;
  int drow = tid>>2, dq = tid&3;      // for dst-dot epilogue
  float acc[4][4]={};
  float asd0=0.f, asd1=0.f, asd2=0.f;
  for (int k0=0;k0<K;k0+=64){
    #pragma unroll
    for (int p=0;p<4;p++){
      int r = (tid>>4) + 16*p;
      int c = (tid&15)*4;
      int gr = row0 + r;
      float4 xv = make_float4(0.f,0.f,0.f,0.f);
      if (gr < Ns) xv = *(const float4*)(X + (long)gr*K + k0 + c);
      sX[r][c]=xv.x; sX[r][c+1]=xv.y; sX[r][c+2]=xv.z; sX[r][c+3]=xv.w;
      float4 wv4 = *(const float4*)(W + (long)(k0+r)*64 + c);
      *(float4*)&sW[r][c] = wv4;
    }
    __syncthreads();
    #pragma unroll 8
    for (int k=0;k<64;k++){
      float a0=sX[tr*4+0][k],a1=sX[tr*4+1][k],a2=sX[tr*4+2][k],a3=sX[tr*4+3][k];
      float4 b4 = *(const float4*)&sW[k][tc*4];
      acc[0][0]+=a0*b4.x; acc[0][1]+=a0*b4.y; acc[0][2]+=a0*b4.z; acc[0][3]+=a0*b4.w;
      acc[1][0]+=a1*b4.x; acc[1][1]+=a1*b4.y; acc[1][2]+=a1*b4.z; acc[1][3]+=a1*b4.w;
      acc[2][0]+=a2*b4.x; acc[2][1]+=a2*b4.y; acc[2][2]+=a2*b4.z; acc[2][3]+=a2*b4.w;
      acc[3][0]+=a3*b4.x; acc[3][1]+=a3*b4.y; acc[3][2]+=a3*b4.z; acc[3][3]+=a3*b4.w;
    }
    if (nj) {
      int kb = dq*16;
      #pragma unroll
      for (int kk=0; kk<16; kk++){
        float xv = sX[drow][kb+kk];
        asd0 += xv * wvA[k0+kb+kk];
        asd1 += xv * wvB[k0+kb+kk];
        asd2 += xv * wvC[k0+kb+kk];
      }
    }
    __syncthreads();
  }
  if (nj) {
    sdd[0][drow][dq]=asd0;
    sdd[1][drow][dq]=asd1;
    sdd[2][drow][dq]=asd2;
    __syncthreads();
    if (tid < 64) {
      int r = row0 + tid;
      if (r < Ns) {
        for (int j=0;j<nj;j++) {
          float s = sdd[j][tid][0]+sdd[j][tid][1]+sdd[j][tid][2]+sdd[j][tid][3];
          t.sdst[gRB[gTG[et][j]] + r] = s;
        }
      }
    }
  }
  float a4[4];
  #pragma unroll
  for (int j=0;j<4;j++) a4[j]=avec[tc*4+j];
  #pragma unroll
  for (int i=0;i<4;i++){
    int r = row0 + tr*4 + i;
    if (r < Ns){
      float4 o; o.x=acc[i][0]; o.y=acc[i][1]; o.z=acc[i][2]; o.w=acc[i][3];
      *(float4*)(HS + (long)r*64 + tc*4) = o;
    }
    float sc = acc[i][0]*a4[0]+acc[i][1]*a4[1]+acc[i][2]*a4[2]+acc[i][3]*a4[3];
    #pragma unroll
    for (int off=1;off<16;off<<=1) sc += __shfl_xor(sc, off);
    if (tc==0 && r<Ns) score[r]=sc;
  }
}

// fused aggregation: one wave per dst node; loops incoming edge types;
// applies bias + relu; writes final layer output.
__global__ __launch_bounds__(256) void k_agg_all(AggTab t) {
  int node = blockIdx.x*4 + (threadIdx.x>>6);
  int lane = threadIdx.x & 63;
  if (node >= NTOT) return;
  int ty = (node>=5000)+(node>=55000)+(node>=155000)+(node>=305000);
  int r = node - gTOFF[ty];
  float outacc = 0.f;
  int ne = gNIN[ty];
  for (int ii=0; ii<ne; ii++) {
    int et = gINET[ty][ii];
    float sd = t.sdst[gRB[et] + r];
    int ob = gOB[et];
    int beg = t.offs[ob + r];
    int end = t.offs[ob + r + 1];
    if (beg < end) {
      const int* cs = t.csr + gEB[et];
      int sb = gSB[et];
      const float* ss = t.ssrc + sb;
      const float* hsb = t.hs + (long)sb*64;
      float m = -3.0e38f;
      for (int e=beg+lane; e<end; e+=64) {
        float l = ss[cs[e]] + sd;
        l = (l>0.f)? l : 0.2f*l;
        m = fmaxf(m,l);
      }
      #pragma unroll
      for (int off=32;off;off>>=1) m = fmaxf(m,__shfl_xor(m,off));
      float den=0.f, acc=0.f;
      int e = beg;
      for (; e+4<=end; e+=4){
        int s0=cs[e], s1=cs[e+1], s2=cs[e+2], s3=cs[e+3];
        float l0=ss[s0]+sd; l0=(l0>0.f)?l0:0.2f*l0;
        float l1=ss[s1]+sd; l1=(l1>0.f)?l1:0.2f*l1;
        float l2=ss[s2]+sd; l2=(l2>0.f)?l2:0.2f*l2;
        float l3=ss[s3]+sd; l3=(l3>0.f)?l3:0.2f*l3;
        float x0=__expf(l0-m), x1=__expf(l1-m);
        float x2=__expf(l2-m), x3=__expf(l3-m);
        den += (x0+x1)+(x2+x3);
        const float* h0 = hsb + (long)s0*64;
        const float* h1 = hsb + (long)s1*64;
        const float* h2 = hsb + (long)s2*64;
        const float* h3 = hsb + (long)s3*64;
        acc += x0*h0[lane];
        acc += x1*h1[lane];
        acc += x2*h2[lane];
        acc += x3*h3[lane];
      }
      for (; e<end; e++){
        int s = cs[e];
        float l = ss[s]+sd; l=(l>0.f)?l:0.2f*l;
        float ex = __expf(l-m);
        den += ex;
        acc += ex*hsb[(long)s*64+lane];
      }
      outacc += acc/(den+1e-16f);
    }
  }
  float o = outacc + t.bsum[ty*64+lane];
  t.xout[(long)node*64+lane] = fmaxf(o,0.f);
}

// ---------------- pooling + head ----------------
__global__ __launch_bounds__(64) void k_pool(PoolTab t, float* __restrict__ pooled) {
  int g = blockIdx.x; int ty = blockIdx.y; int lane = threadIdx.x;
  const int* batch = t.batch[ty];
  int n = t.nt[ty];
  int lo=0, hi=0;
  if (lane==0){
    int a=0,b2=n;
    while(a<b2){int mm=(a+b2)>>1; if (batch[mm]<g) a=mm+1; else b2=mm;}
    lo=a;
    a=lo; b2=n;
    while(a<b2){int mm=(a+b2)>>1; if (batch[mm]<g+1) a=mm+1; else b2=mm;}
    hi=a;
  }
  lo=__shfl(lo,0); hi=__shfl(hi,0);
  const float* x = t.x[ty];
  float acc=0.f;
  for (int i=lo;i<hi;i++) acc += x[(long)i*64+lane];
  int cnt = hi-lo;
  pooled[(long)g*320 + ty*64 + lane] = acc / (float)(cnt>0?cnt:1);
}

__global__ __launch_bounds__(256) void k_final(
    const float* __restrict__ pooled, const float* __restrict__ post,
    const float* __restrict__ Wlin, const float* __restrict__ blin,
    float* __restrict__ out)
{
  int w = (blockIdx.x*256+threadIdx.x)>>6;
  int lane = threadIdx.x&63;
  if (w>=GDIM) return;
  float a0=0.f,a1=0.f;
  for (int k=lane;k<320+PDIM;k+=64){
    float v = (k<320) ? pooled[(long)w*320+k] : post[(long)w*PDIM + (k-320)];
    a0 += v*Wlin[k*2];
    a1 += v*Wlin[k*2+1];
  }
  #pragma unroll
  for (int off=32;off;off>>=1){ a0+=__shfl_xor(a0,off); a1+=__shfl_xor(a1,off); }
  if (lane==0){
    float z0=a0+blin[0], z1=a1+blin[1];
    z0=fmaxf(z0,0.f); z1=fmaxf(z1,0.f);
    float mm=fmaxf(z0,z1);
    float e0=__expf(z0-mm), e1=__expf(z1-mm);
    float inv = 1.f/(e0+e1);
    out[w*2+0]=e0*inv; out[w*2+1]=e1*inv;
  }
}

extern "C" void kernel_launch(void* const* d_in, const int* in_sizes, int n_in,
                              void* d_out, int out_size, void* d_ws, size_t ws_size,
                              hipStream_t stream) {
  (void)in_sizes; (void)n_in; (void)out_size; (void)ws_size;
  char* ws = (char*)d_ws;
  size_t off = 0;
  auto A = [&](size_t nbytes){ size_t o=off; off=(off+nbytes+255)&~((size_t)255); return o; };
  size_t xbuf1_o = A((size_t)NTOT*64*4);        // 78.6 MB
  size_t xbuf2_o = A((size_t)NTOT*64*4);        // 78.6 MB
  size_t hs_o    = A((size_t)469000*64*4);      // 120 MB
  size_t csr_o   = A((size_t)ETOT*4);           // 27.2 MB
  size_t offs_o  = A((size_t)469010*4);
  size_t cur_o   = A((size_t)469010*4);
  size_t cnt_o   = A((size_t)469000*4);
  size_t ssrc_o  = A((size_t)469000*4);
  size_t sdst_o  = A((size_t)469000*4);
  size_t pool_o  = A((size_t)GDIM*320*4);
  size_t wv_o    = A((size_t)NET*256*4);
  size_t bsum_o  = A((size_t)320*4);
  size_t part_o  = A((size_t)460*4);

  float* xbuf1 = (float*)(ws + xbuf1_o);
  float* xbuf2 = (float*)(ws + xbuf2_o);
  float* hsB   = (float*)(ws + hs_o);
  int*   csr   = (int*)(ws + csr_o);
  int*   offs  = (int*)(ws + offs_o);
  int*   cur   = (int*)(ws + cur_o);
  int*   cnts  = (int*)(ws + cnt_o);
  float* ssrcB = (float*)(ws + ssrc_o);
  float* sdstA = (float*)(ws + sdst_o);
  float* pooled= (float*)(ws + pool_o);
  float* wv    = (float*)(ws + wv_o);
  float* bsum  = (float*)(ws + bsum_o);
  int*   parts = (int*)(ws + part_o);

  int kOB[NET];
  for (int i=0;i<NET;i++) kOB[i] = kRB[i] + i;

  // ---- build CSR (edge structure is layer-invariant) ----
  EdgeTab et;
  for (int i=0;i<NET;i++) et.ei[i] = (const int*)d_in[6+i];
  for (int i=0;i<=NET;i++) { et.ebase[i]=kEB[i]; et.rbase[i]=kRB[i]; }
  for (int i=0;i<NET;i++) et.obase[i]=kOB[i];

  ScanTab st;
  for (int i=0;i<=NET;i++) st.bbase[i]=kBB[i];
  for (int i=0;i<NET;i++) { st.cbase[i]=kRB[i]; st.obase[i]=kOB[i]; st.pbase[i]=kBB[i]; st.nd[i]=kND[i]; st.ec[i]=kEC[i]; }

  hipMemsetAsync(cnts, 0, (size_t)469000*4, stream);
  int egrid = (ETOT+255)/256;
  k_hist<<<egrid,256,0,stream>>>(et, cnts);
  k_scan1<<<kBB[NET],256,0,stream>>>(st, cnts, offs, parts);
  k_scan2<<<NET,256,0,stream>>>(st, parts);
  k_scan3<<<kBB[NET],256,0,stream>>>(st, offs, parts);
  hipMemcpyAsync(cur, offs, (size_t)469010*4, hipMemcpyDeviceToDevice, stream);
  k_scatter<<<egrid,256,0,stream>>>(et, cur, csr);

  BiasTab bt; for (int i=0;i<NET;i++) bt.dstt[i]=kDSTT2[i];

  // ---- two GAT layers ----
  for (int l=0;l<2;l++){
    const float* Wsrc = (const float*)d_in[21+5*l];
    const float* Wdst = (const float*)d_in[22+5*l];
    const float* asrc = (const float*)d_in[23+5*l];
    const float* adst = (const float*)d_in[24+5*l];
    const float* bb   = (const float*)d_in[25+5*l];
    int K = l ? 64 : 256;
    const float* xin[NTY];
    float* xout = l ? xbuf2 : xbuf1;
    for (int t=0;t<NTY;t++)
      xin[t] = l ? (const float*)(xbuf1 + (long)kTOFF[t]*64) : (const float*)d_in[t];

    k_bias<<<1,320,0,stream>>>(bb, bt, bsum);
    k_wdst<<<NET,K,0,stream>>>(Wdst, adst, wv, K);

    GemmTab gt;
    for (int e=0;e<NET;e++) gt.X[e] = xin[kSRCT[e]];
    gt.Wsrc = Wsrc; gt.asrc = asrc; gt.wv = wv;
    gt.hs = hsB; gt.ssrc = ssrcB; gt.sdst = sdstA; gt.K = K;
    k_gemm_all<<<kGB[NET],256,0,stream>>>(gt);

    AggTab at;
    at.offs = offs; at.csr = csr; at.hs = hsB; at.ssrc = ssrcB;
    at.sdst = sdstA; at.bsum = bsum; at.xout = xout;
    k_agg_all<<<(NTOT+3)/4,256,0,stream>>>(at);
  }

  // ---- pooling + head ----
  PoolTab pt;
  for (int t=0;t<NTY;t++){
    pt.batch[t] = (const int*)d_in[16+t];
    pt.x[t] = (const float*)(xbuf2 + (long)kTOFF[t]*64);
    pt.nt[t] = kNT[t];
  }
  dim3 pgrid(GDIM, NTY);
  k_pool<<<pgrid,64,0,stream>>>(pt, pooled);

  k_final<<<GDIM/4,256,0,stream>>>(pooled, (const float*)d_in[5],
                                   (const float*)d_in[31], (const float*)d_in[32],
                                   (float*)d_out);
}

// Round 4
// 1760.361 us; speedup vs baseline: 1.7633x; 1.1885x over previous
//
#include <hip/hip_runtime.h>
#include <math.h>

#define NTY 5
#define NET 10
#define NTOT 307000
#define ETOT 6800000
#define GDIM 1024
#define PDIM 768
#define NGEMMB 7335
#define NSCATB 26563
#define NMEGAB (NGEMMB + NSCATB)

// ---- compile-time problem tables (host) ----
static const int kSRCT[NET]= {0,0,0,4,4,1,2,3,1,2};
static const int kNT[NTY]  = {5000,50000,100000,150000,2000};
static const int kTOFF[NTY]= {0,5000,55000,155000,305000};
static const int kEB[NET+1]= {0,500000,1500000,2500000,2800000,3400000,3900000,4900000,5900000,6200000,6800000};
static const int kRB[NET+1]= {0,50000,150000,300000,350000,450000,455000,460000,465000,467000,469000};
static const int kBB[NET+1]= {0,49,147,294,343,441,446,451,456,458,460};
static const int kND[NET]  = {50000,100000,150000,50000,100000,5000,5000,5000,2000,2000};
static const int kEC[NET]  = {500000,1000000,1000000,300000,600000,500000,1000000,1000000,300000,600000};

// ---- device tables ----
__device__ const int gOB[NET]   = {0,50001,150002,300003,350004,450005,455006,460007,465008,467009};
__device__ const int gEB[NET+1] = {0,500000,1500000,2500000,2800000,3400000,3900000,4900000,5900000,6200000,6800000};
__device__ const int gSB[NET]   = {0,5000,10000,15000,17000,19000,69000,169000,319000,369000};
__device__ const int gRB[NET]   = {0,50000,150000,300000,350000,450000,455000,460000,465000,467000};
__device__ const int gTOFF[NTY] = {0,5000,55000,155000,305000};
__device__ const int gNIN[NTY]  = {3,2,2,1,2};
__device__ const int gINET[NTY][3] = {{5,6,7},{0,3,0},{1,4,0},{2,0,0},{8,9,0}};
__device__ const int gNJ[NET]   = {3,0,0,2,0,2,2,1,0,0};
__device__ const int gTG[NET][3]= {{5,6,7},{0,0,0},{0,0,0},{8,9,0},{0,0,0},{0,3,0},{1,4,0},{2,0,0},{0,0,0},{0,0,0}};
__device__ const int gDSTT[NET] = {1,2,3,1,2,0,0,0,4,4};

struct EdgeTab {
  const int* ei[NET];
  int ebase[NET+1];
  int obase[NET];
  int rbase[NET+1];
};
struct ScanTab {
  int bbase[NET+1];
  int cbase[NET];
  int obase[NET];
  int pbase[NET];
  int nd[NET];
  int ec[NET];
};
struct PrepTab {
  const float* Wd0; const float* ad0; const float* b0;
  const float* Wd1; const float* ad1; const float* b1;
  float* wv0; float* wv1; float* bs0; float* bs1;
};
struct PoolTab { const int* batch[NTY]; const float* x[NTY]; int nt[NTY]; };
struct GemmArgs {
  const float* X[NET];
  const float* Wsrc;
  const float* asrc;
  const float* wv;
  float* hs;
  float* ssrc;
  float* sdst;
  int K;
};
struct MegaTab {
  GemmArgs g;
  const int* ei[NET];
  int* cursor;
  int* csr;
};
struct AggTab {
  const int* offs;
  const int* csr;
  const float* hs;
  const float* ssrc;
  const float* sdst;
  const float* bsum;
  float* xout;
};

// ---------------- hist + weight-prep ----------------
__global__ __launch_bounds__(256) void k_histprep(EdgeTab t, int* __restrict__ counts, PrepTab p) {
  int b = blockIdx.x;
  int tid = threadIdx.x;
  if (b == 0) {
    // layer0: wv0[et*256+k] = Wdst0[et,k,:] . adst0[et,:]   (K=256)
    for (int e2=0; e2<NET; e2++){
      const float* W = p.Wd0 + (long)e2*256*64;
      const float* a = p.ad0 + e2*64;
      float s=0.f;
      #pragma unroll 8
      for (int c=0;c<64;c++) s += W[tid*64+c]*a[c];
      p.wv0[e2*256+tid]=s;
    }
    for (int idx=tid; idx<320; idx+=256){
      int ty=idx>>6, c=idx&63; float s=0.f;
      #pragma unroll
      for (int i=0;i<NET;i++) if (gDSTT[i]==ty) s += p.b0[i*64+c];
      p.bs0[idx]=s;
    }
    return;
  }
  if (b == 1) {
    if (tid < 64){
      for (int e2=0; e2<NET; e2++){
        const float* W = p.Wd1 + (long)e2*64*64;
        const float* a = p.ad1 + e2*64;
        float s=0.f;
        #pragma unroll 8
        for (int c=0;c<64;c++) s += W[tid*64+c]*a[c];
        p.wv1[e2*256+tid]=s;
      }
    }
    for (int idx=tid; idx<320; idx+=256){
      int ty=idx>>6, c=idx&63; float s=0.f;
      #pragma unroll
      for (int i=0;i<NET;i++) if (gDSTT[i]==ty) s += p.b1[i*64+c];
      p.bs1[idx]=s;
    }
    return;
  }
  int gid = (b-2)*256 + tid;
  if (gid >= t.ebase[NET]) return;
  int et = 0;
  #pragma unroll
  for (int i=0;i<NET;i++) if (gid >= t.ebase[i+1]) et = i+1;
  int e = gid - t.ebase[et];
  int E = t.ebase[et+1]-t.ebase[et];
  int dst = t.ei[et][E + e];
  atomicAdd(&counts[t.rbase[et] + dst], 1);
}

// ---------------- scans ----------------
__global__ __launch_bounds__(256) void k_scan1(ScanTab t, const int* __restrict__ counts,
                                               int* __restrict__ offs, int* __restrict__ partials) {
  __shared__ int sd[256];
  int b = blockIdx.x;
  int et = 0;
  #pragma unroll
  for (int i=0;i<NET;i++) if (b >= t.bbase[i+1]) et = i+1;
  int lb = b - t.bbase[et];
  int n = t.nd[et];
  const int* cin = counts + t.cbase[et];
  int* oo = offs + t.obase[et];
  int tid = threadIdx.x;
  int base = lb*1024 + tid*4;
  int v0 = (base+0<n)?cin[base+0]:0;
  int v1 = (base+1<n)?cin[base+1]:0;
  int v2 = (base+2<n)?cin[base+2]:0;
  int v3 = (base+3<n)?cin[base+3]:0;
  int tsum = v0+v1+v2+v3;
  sd[tid]=tsum; __syncthreads();
  for (int off=1; off<256; off<<=1) {
    int x = (tid>=off)? sd[tid-off] : 0;
    __syncthreads();
    sd[tid] += x;
    __syncthreads();
  }
  int run = sd[tid]-tsum;
  if (tid==255) partials[t.pbase[et]+lb]=sd[255];
  if (base+0<n){ oo[base+0]=run; run+=v0; }
  if (base+1<n){ oo[base+1]=run; run+=v1; }
  if (base+2<n){ oo[base+2]=run; run+=v2; }
  if (base+3<n){ oo[base+3]=run; }
}

__global__ __launch_bounds__(256) void k_scan2(ScanTab t, int* __restrict__ partials) {
  __shared__ int sd[256];
  int et = blockIdx.x;
  int nb = t.bbase[et+1]-t.bbase[et];
  int tid = threadIdx.x;
  int v = (tid<nb)? partials[t.pbase[et]+tid] : 0;
  sd[tid]=v; __syncthreads();
  for (int off=1; off<256; off<<=1) {
    int x=(tid>=off)?sd[tid-off]:0;
    __syncthreads();
    sd[tid]+=x;
    __syncthreads();
  }
  if (tid<nb) partials[t.pbase[et]+tid] = sd[tid]-v;
}

__global__ __launch_bounds__(256) void k_scan3(ScanTab t, int* __restrict__ offs,
                                               const int* __restrict__ partials) {
  int b = blockIdx.x;
  int et=0;
  #pragma unroll
  for (int i=0;i<NET;i++) if (b>=t.bbase[i+1]) et=i+1;
  int lb = b - t.bbase[et];
  int n = t.nd[et];
  int* oo = offs + t.obase[et];
  int add = partials[t.pbase[et]+lb];
  int tid = threadIdx.x;
  int base = lb*1024 + tid*4;
  #pragma unroll
  for (int j=0;j<4;j++) if (base+j<n) oo[base+j]+=add;
  if (lb==0 && tid==0) oo[n] = t.ec[et];
}

// ---------------- gemm body (shared by mega + layer1) ----------------
__device__ __forceinline__ void gemm_block(const GemmArgs& t, int b) {
  __shared__ float sX[64][68];
  __shared__ float sW[64][64];
  __shared__ float sdd[3][64][4];
  const int GB1=79,GB2=158,GB3=237,GB4=269,GB5=301,GB6=1083,GB7=2646,GB8=4990,GB9=5772;
  int et = (b>=GB1)+(b>=GB2)+(b>=GB3)+(b>=GB4)+(b>=GB5)+(b>=GB6)+(b>=GB7)+(b>=GB8)+(b>=GB9);
  const int GBb[NET] = {0,GB1,GB2,GB3,GB4,GB5,GB6,GB7,GB8,GB9};
  const int NSa[NET] = {5000,5000,5000,2000,2000,50000,100000,150000,50000,100000};
  int lb = b - GBb[et];
  int Ns = NSa[et];
  int K = t.K;
  const float* X = t.X[et];
  const float* W = t.Wsrc + (long)et*K*64;
  const float* avec = t.asrc + et*64;
  int sbase = gSB[et];
  float* HS = t.hs + (long)sbase*64;
  float* score = t.ssrc + sbase;

  int nj = gNJ[et];
  const float* wvA = t.wv + gTG[et][0]*256;
  const float* wvB = t.wv + gTG[et][1]*256;
  const float* wvC = t.wv + gTG[et][2]*256;

  int tid = threadIdx.x;
  int row0 = lb*64;
  int tr = tid>>4, tc = tid&15;
  int drow = tid>>2, dq = tid&3;
  float acc[4][4]={};
  float asd0=0.f, asd1=0.f, asd2=0.f;
  for (int k0=0;k0<K;k0+=64){
    #pragma unroll
    for (int p=0;p<4;p++){
      int r = (tid>>4) + 16*p;
      int c = (tid&15)*4;
      int gr = row0 + r;
      float4 xv = make_float4(0.f,0.f,0.f,0.f);
      if (gr < Ns) xv = *(const float4*)(X + (long)gr*K + k0 + c);
      sX[r][c]=xv.x; sX[r][c+1]=xv.y; sX[r][c+2]=xv.z; sX[r][c+3]=xv.w;
      float4 wv4 = *(const float4*)(W + (long)(k0+r)*64 + c);
      *(float4*)&sW[r][c] = wv4;
    }
    __syncthreads();
    #pragma unroll 8
    for (int k=0;k<64;k++){
      float a0=sX[tr*4+0][k],a1=sX[tr*4+1][k],a2=sX[tr*4+2][k],a3=sX[tr*4+3][k];
      float4 b4 = *(const float4*)&sW[k][tc*4];
      acc[0][0]+=a0*b4.x; acc[0][1]+=a0*b4.y; acc[0][2]+=a0*b4.z; acc[0][3]+=a0*b4.w;
      acc[1][0]+=a1*b4.x; acc[1][1]+=a1*b4.y; acc[1][2]+=a1*b4.z; acc[1][3]+=a1*b4.w;
      acc[2][0]+=a2*b4.x; acc[2][1]+=a2*b4.y; acc[2][2]+=a2*b4.z; acc[2][3]+=a2*b4.w;
      acc[3][0]+=a3*b4.x; acc[3][1]+=a3*b4.y; acc[3][2]+=a3*b4.z; acc[3][3]+=a3*b4.w;
    }
    if (nj) {
      int kb = dq*16;
      #pragma unroll
      for (int kk=0; kk<16; kk++){
        float xv = sX[drow][kb+kk];
        asd0 += xv * wvA[k0+kb+kk];
        asd1 += xv * wvB[k0+kb+kk];
        asd2 += xv * wvC[k0+kb+kk];
      }
    }
    __syncthreads();
  }
  if (nj) {
    sdd[0][drow][dq]=asd0;
    sdd[1][drow][dq]=asd1;
    sdd[2][drow][dq]=asd2;
    __syncthreads();
    if (tid < 64) {
      int r = row0 + tid;
      if (r < Ns) {
        for (int j=0;j<nj;j++) {
          float s = sdd[j][tid][0]+sdd[j][tid][1]+sdd[j][tid][2]+sdd[j][tid][3];
          t.sdst[gRB[gTG[et][j]] + r] = s;
        }
      }
    }
  }
  float a4[4];
  #pragma unroll
  for (int j=0;j<4;j++) a4[j]=avec[tc*4+j];
  #pragma unroll
  for (int i=0;i<4;i++){
    int r = row0 + tr*4 + i;
    if (r < Ns){
      float4 o; o.x=acc[i][0]; o.y=acc[i][1]; o.z=acc[i][2]; o.w=acc[i][3];
      *(float4*)(HS + (long)r*64 + tc*4) = o;
    }
    float sc = acc[i][0]*a4[0]+acc[i][1]*a4[1]+acc[i][2]*a4[2]+acc[i][3]*a4[3];
    #pragma unroll
    for (int off=1;off<16;off<<=1) sc += __shfl_xor(sc, off);
    if (tc==0 && r<Ns) score[r]=sc;
  }
}

__global__ __launch_bounds__(256) void k_gemm_all(GemmArgs t) {
  gemm_block(t, blockIdx.x);
}

// ---------------- mega: scatter + layer-0 gemm interleaved ----------------
__global__ __launch_bounds__(256) void k_mega0(MegaTab t) {
  long long b = blockIdx.x;
  const long long G = NGEMMB, T = NMEGAB;
  long long lo = (b*G)/T, hi = ((b+1)*G)/T;
  if (hi > lo) {
    gemm_block(t.g, (int)lo);
  } else {
    int sidx = (int)(b - lo);
    int gid = sidx*256 + threadIdx.x;
    if (gid >= ETOT) return;
    int et=0;
    #pragma unroll
    for (int i=0;i<NET;i++) if (gid>=gEB[i+1]) et=i+1;
    int e = gid - gEB[et];
    int E = gEB[et+1]-gEB[et];
    int src = t.ei[et][e];
    int dst = t.ei[et][E+e];
    int pos = atomicAdd(&t.cursor[gOB[et]+dst], 1);
    t.csr[gEB[et] + pos] = src;
  }
}

// ---------------- fused aggregation (no max pass) ----------------
__global__ __launch_bounds__(256) void k_agg_all(AggTab t) {
  int node = blockIdx.x*4 + (threadIdx.x>>6);
  int lane = threadIdx.x & 63;
  if (node >= NTOT) return;
  int ty = (node>=5000)+(node>=55000)+(node>=155000)+(node>=305000);
  int r = node - gTOFF[ty];
  float outacc = 0.f;
  int ne = gNIN[ty];
  for (int ii=0; ii<ne; ii++) {
    int et = gINET[ty][ii];
    float sd = t.sdst[gRB[et] + r];
    int ob = gOB[et];
    int beg = t.offs[ob + r];
    int end = t.offs[ob + r + 1];
    if (beg >= end) continue;
    const int* cs = t.csr + gEB[et];
    int sb = gSB[et];
    const float* ss = t.ssrc + sb;
    const float* hsb = t.hs + (long)sb*64;
    float den=0.f, acc=0.f;
    int e = beg;
    for (; e+8<=end; e+=8){
      int s0=cs[e+0], s1=cs[e+1], s2=cs[e+2], s3=cs[e+3];
      int s4=cs[e+4], s5=cs[e+5], s6=cs[e+6], s7=cs[e+7];
      float l0=ss[s0]+sd; l0=(l0>0.f)?l0:0.2f*l0;
      float l1=ss[s1]+sd; l1=(l1>0.f)?l1:0.2f*l1;
      float l2=ss[s2]+sd; l2=(l2>0.f)?l2:0.2f*l2;
      float l3=ss[s3]+sd; l3=(l3>0.f)?l3:0.2f*l3;
      float l4=ss[s4]+sd; l4=(l4>0.f)?l4:0.2f*l4;
      float l5=ss[s5]+sd; l5=(l5>0.f)?l5:0.2f*l5;
      float l6=ss[s6]+sd; l6=(l6>0.f)?l6:0.2f*l6;
      float l7=ss[s7]+sd; l7=(l7>0.f)?l7:0.2f*l7;
      float x0=__expf(l0), x1=__expf(l1), x2=__expf(l2), x3=__expf(l3);
      float x4=__expf(l4), x5=__expf(l5), x6=__expf(l6), x7=__expf(l7);
      den += ((x0+x1)+(x2+x3)) + ((x4+x5)+(x6+x7));
      acc += x0*hsb[(long)s0*64+lane];
      acc += x1*hsb[(long)s1*64+lane];
      acc += x2*hsb[(long)s2*64+lane];
      acc += x3*hsb[(long)s3*64+lane];
      acc += x4*hsb[(long)s4*64+lane];
      acc += x5*hsb[(long)s5*64+lane];
      acc += x6*hsb[(long)s6*64+lane];
      acc += x7*hsb[(long)s7*64+lane];
    }
    for (; e<end; e++){
      int s = cs[e];
      float l = ss[s]+sd; l=(l>0.f)?l:0.2f*l;
      float ex = __expf(l);
      den += ex;
      acc += ex*hsb[(long)s*64+lane];
    }
    outacc += acc/(den+1e-16f);
  }
  float o = outacc + t.bsum[ty*64+lane];
  t.xout[(long)node*64+lane] = fmaxf(o,0.f);
}

// ---------------- pooling + head ----------------
__global__ __launch_bounds__(64) void k_pool(PoolTab t, float* __restrict__ pooled) {
  int g = blockIdx.x; int ty = blockIdx.y; int lane = threadIdx.x;
  const int* batch = t.batch[ty];
  int n = t.nt[ty];
  int lo=0, hi=0;
  if (lane==0){
    int a=0,b2=n;
    while(a<b2){int mm=(a+b2)>>1; if (batch[mm]<g) a=mm+1; else b2=mm;}
    lo=a;
    a=lo; b2=n;
    while(a<b2){int mm=(a+b2)>>1; if (batch[mm]<g+1) a=mm+1; else b2=mm;}
    hi=a;
  }
  lo=__shfl(lo,0); hi=__shfl(hi,0);
  const float* x = t.x[ty];
  float acc=0.f;
  for (int i=lo;i<hi;i++) acc += x[(long)i*64+lane];
  int cnt = hi-lo;
  pooled[(long)g*320 + ty*64 + lane] = acc / (float)(cnt>0?cnt:1);
}

__global__ __launch_bounds__(256) void k_final(
    const float* __restrict__ pooled, const float* __restrict__ post,
    const float* __restrict__ Wlin, const float* __restrict__ blin,
    float* __restrict__ out)
{
  int w = (blockIdx.x*256+threadIdx.x)>>6;
  int lane = threadIdx.x&63;
  if (w>=GDIM) return;
  float a0=0.f,a1=0.f;
  for (int k=lane;k<320+PDIM;k+=64){
    float v = (k<320) ? pooled[(long)w*320+k] : post[(long)w*PDIM + (k-320)];
    a0 += v*Wlin[k*2];
    a1 += v*Wlin[k*2+1];
  }
  #pragma unroll
  for (int off=32;off;off>>=1){ a0+=__shfl_xor(a0,off); a1+=__shfl_xor(a1,off); }
  if (lane==0){
    float z0=a0+blin[0], z1=a1+blin[1];
    z0=fmaxf(z0,0.f); z1=fmaxf(z1,0.f);
    float mm=fmaxf(z0,z1);
    float e0=__expf(z0-mm), e1=__expf(z1-mm);
    float inv = 1.f/(e0+e1);
    out[w*2+0]=e0*inv; out[w*2+1]=e1*inv;
  }
}

extern "C" void kernel_launch(void* const* d_in, const int* in_sizes, int n_in,
                              void* d_out, int out_size, void* d_ws, size_t ws_size,
                              hipStream_t stream) {
  (void)in_sizes; (void)n_in; (void)out_size; (void)ws_size;
  char* ws = (char*)d_ws;
  size_t off = 0;
  auto A = [&](size_t nbytes){ size_t o=off; off=(off+nbytes+255)&~((size_t)255); return o; };
  size_t xbuf1_o = A((size_t)NTOT*64*4);
  size_t xbuf2_o = A((size_t)NTOT*64*4);
  size_t hs_o    = A((size_t)469000*64*4);
  size_t csr_o   = A((size_t)ETOT*4);
  size_t offs_o  = A((size_t)469010*4);
  size_t cur_o   = A((size_t)469010*4);
  size_t cnt_o   = A((size_t)469000*4);
  size_t ssrc_o  = A((size_t)469000*4);
  size_t sdst_o  = A((size_t)469000*4);
  size_t pool_o  = A((size_t)GDIM*320*4);
  size_t wv0_o   = A((size_t)NET*256*4);
  size_t wv1_o   = A((size_t)NET*256*4);
  size_t bs0_o   = A((size_t)320*4);
  size_t bs1_o   = A((size_t)320*4);
  size_t part_o  = A((size_t)460*4);

  float* xbuf1 = (float*)(ws + xbuf1_o);
  float* xbuf2 = (float*)(ws + xbuf2_o);
  float* hsB   = (float*)(ws + hs_o);
  int*   csr   = (int*)(ws + csr_o);
  int*   offs  = (int*)(ws + offs_o);
  int*   cur   = (int*)(ws + cur_o);
  int*   cnts  = (int*)(ws + cnt_o);
  float* ssrcB = (float*)(ws + ssrc_o);
  float* sdstA = (float*)(ws + sdst_o);
  float* pooled= (float*)(ws + pool_o);
  float* wv0   = (float*)(ws + wv0_o);
  float* wv1   = (float*)(ws + wv1_o);
  float* bs0   = (float*)(ws + bs0_o);
  float* bs1   = (float*)(ws + bs1_o);
  int*   parts = (int*)(ws + part_o);

  int kOB[NET];
  for (int i=0;i<NET;i++) kOB[i] = kRB[i] + i;

  EdgeTab et;
  for (int i=0;i<NET;i++) et.ei[i] = (const int*)d_in[6+i];
  for (int i=0;i<=NET;i++) { et.ebase[i]=kEB[i]; et.rbase[i]=kRB[i]; }
  for (int i=0;i<NET;i++) et.obase[i]=kOB[i];

  ScanTab st;
  for (int i=0;i<=NET;i++) st.bbase[i]=kBB[i];
  for (int i=0;i<NET;i++) { st.cbase[i]=kRB[i]; st.obase[i]=kOB[i]; st.pbase[i]=kBB[i]; st.nd[i]=kND[i]; st.ec[i]=kEC[i]; }

  PrepTab pp;
  pp.Wd0 = (const float*)d_in[22]; pp.ad0 = (const float*)d_in[24]; pp.b0 = (const float*)d_in[25];
  pp.Wd1 = (const float*)d_in[27]; pp.ad1 = (const float*)d_in[29]; pp.b1 = (const float*)d_in[30];
  pp.wv0 = wv0; pp.wv1 = wv1; pp.bs0 = bs0; pp.bs1 = bs1;

  hipMemsetAsync(cnts, 0, (size_t)469000*4, stream);
  k_histprep<<<2+NSCATB,256,0,stream>>>(et, cnts, pp);
  k_scan1<<<kBB[NET],256,0,stream>>>(st, cnts, offs, parts);
  k_scan2<<<NET,256,0,stream>>>(st, parts);
  k_scan3<<<kBB[NET],256,0,stream>>>(st, offs, parts);
  hipMemcpyAsync(cur, offs, (size_t)469010*4, hipMemcpyDeviceToDevice, stream);

  // ---- mega: scatter + layer-0 gemm ----
  MegaTab mt;
  for (int e=0;e<NET;e++) mt.g.X[e] = (const float*)d_in[kSRCT[e]];
  mt.g.Wsrc = (const float*)d_in[21];
  mt.g.asrc = (const float*)d_in[23];
  mt.g.wv = wv0; mt.g.hs = hsB; mt.g.ssrc = ssrcB; mt.g.sdst = sdstA; mt.g.K = 256;
  for (int i=0;i<NET;i++) mt.ei[i] = (const int*)d_in[6+i];
  mt.cursor = cur; mt.csr = csr;
  k_mega0<<<NMEGAB,256,0,stream>>>(mt);

  // ---- layer-0 agg ----
  AggTab a0;
  a0.offs = offs; a0.csr = csr; a0.hs = hsB; a0.ssrc = ssrcB;
  a0.sdst = sdstA; a0.bsum = bs0; a0.xout = xbuf1;
  k_agg_all<<<(NTOT+3)/4,256,0,stream>>>(a0);

  // ---- layer-1 gemm ----
  GemmArgs g1;
  for (int e=0;e<NET;e++) g1.X[e] = (const float*)(xbuf1 + (long)kTOFF[kSRCT[e]]*64);
  g1.Wsrc = (const float*)d_in[26];
  g1.asrc = (const float*)d_in[28];
  g1.wv = wv1; g1.hs = hsB; g1.ssrc = ssrcB; g1.sdst = sdstA; g1.K = 64;
  k_gemm_all<<<NGEMMB,256,0,stream>>>(g1);

  // ---- layer-1 agg ----
  AggTab a1;
  a1.offs = offs; a1.csr = csr; a1.hs = hsB; a1.ssrc = ssrcB;
  a1.sdst = sdstA; a1.bsum = bs1; a1.xout = xbuf2;
  k_agg_all<<<(NTOT+3)/4,256,0,stream>>>(a1);

  // ---- pooling + head ----
  PoolTab pt;
  for (int t=0;t<NTY;t++){
    pt.batch[t] = (const int*)d_in[16+t];
    pt.x[t] = (const float*)(xbuf2 + (long)kTOFF[t]*64);
    pt.nt[t] = kNT[t];
  }
  dim3 pgrid(GDIM, NTY);
  k_pool<<<pgrid,64,0,stream>>>(pt, pooled);

  k_final<<<GDIM/4,256,0,stream>>>(pooled, (const float*)d_in[5],
                                   (const float*)d_in[31], (const float*)d_in[32],
                                   (float*)d_out);
}

// Round 5
// 1624.827 us; speedup vs baseline: 1.9104x; 1.0834x over previous
//
#include <hip/hip_runtime.h>
#include <math.h>

#define NTY 5
#define NET 10
#define NTOT 307000
#define ETOT 6800000
#define GDIM 1024
#define PDIM 768
#define NGEMMB 7335
#define NSCATB 13282            /* 2 edges/thread */
#define NMEGAB (NGEMMB + NSCATB)

// ---- compile-time problem tables (host) ----
static const int kSRCT[NET]= {0,0,0,4,4,1,2,3,1,2};
static const int kNT[NTY]  = {5000,50000,100000,150000,2000};
static const int kTOFF[NTY]= {0,5000,55000,155000,305000};
static const int kEB[NET+1]= {0,500000,1500000,2500000,2800000,3400000,3900000,4900000,5900000,6200000,6800000};
static const int kRB[NET+1]= {0,50000,150000,300000,350000,450000,455000,460000,465000,467000,469000};
static const int kBB[NET+1]= {0,49,147,294,343,441,446,451,456,458,460};
static const int kND[NET]  = {50000,100000,150000,50000,100000,5000,5000,5000,2000,2000};
static const int kEC[NET]  = {500000,1000000,1000000,300000,600000,500000,1000000,1000000,300000,600000};

// ---- device tables ----
__device__ const int gOB[NET]   = {0,50001,150002,300003,350004,450005,455006,460007,465008,467009};
__device__ const int gEB[NET+1] = {0,500000,1500000,2500000,2800000,3400000,3900000,4900000,5900000,6200000,6800000};
__device__ const int gSB[NET]   = {0,5000,10000,15000,17000,19000,69000,169000,319000,369000};
__device__ const int gRB[NET]   = {0,50000,150000,300000,350000,450000,455000,460000,465000,467000};
__device__ const int gTOFF[NTY] = {0,5000,55000,155000,305000};
__device__ const int gNIN[NTY]  = {3,2,2,1,2};
__device__ const int gINET[NTY][3] = {{5,6,7},{0,3,0},{1,4,0},{2,0,0},{8,9,0}};
__device__ const int gNJ[NET]   = {3,0,0,2,0,2,2,1,0,0};
__device__ const int gTG[NET][3]= {{5,6,7},{0,0,0},{0,0,0},{8,9,0},{0,0,0},{0,3,0},{1,4,0},{2,0,0},{0,0,0},{0,0,0}};
__device__ const int gDSTT[NET] = {1,2,3,1,2,0,0,0,4,4};

__device__ __forceinline__ unsigned short f2bf(float f){
  unsigned int u = __float_as_uint(f);
  u += 0x7fffu + ((u>>16)&1u);
  return (unsigned short)(u>>16);
}
__device__ __forceinline__ float bf2f(unsigned short h){
  return __uint_as_float(((unsigned int)h)<<16);
}

struct EdgeTab {
  const int* ei[NET];
  int ebase[NET+1];
  int obase[NET];
  int rbase[NET+1];
};
struct ScanTab {
  int bbase[NET+1];
  int cbase[NET];
  int obase[NET];
  int pbase[NET];
  int nd[NET];
  int ec[NET];
};
struct PrepTab {
  const float* Wd0; const float* ad0; const float* b0;
  const float* Wd1; const float* ad1; const float* b1;
  float* wv0; float* wv1; float* bs0; float* bs1;
};
struct PoolTab { const int* batch[NTY]; const float* x[NTY]; int nt[NTY]; };
struct GemmArgs {
  const float* X[NET];
  const float* Wsrc;
  const float* asrc;
  const float* wv;
  unsigned short* hs;            // bf16
  float* ssrc;
  float* sdst;
  int K;
};
struct MegaTab {
  GemmArgs g;
  const int* ei[NET];
  int* cursor;
  int* csr;
};
struct AggTab {
  const int* offs;
  const int* csr;
  const unsigned short* hs;      // bf16
  const float* ssrc;
  const float* sdst;
  const float* bsum;
  float* xout;
};

// ---------------- hist (2 edges/thread) + weight-prep ----------------
__global__ __launch_bounds__(256) void k_histprep(EdgeTab t, int* __restrict__ counts, PrepTab p) {
  int b = blockIdx.x;
  int tid = threadIdx.x;
  if (b == 0) {
    for (int e2=0; e2<NET; e2++){
      const float* W = p.Wd0 + (long)e2*256*64;
      const float* a = p.ad0 + e2*64;
      float s=0.f;
      #pragma unroll 8
      for (int c=0;c<64;c++) s += W[tid*64+c]*a[c];
      p.wv0[e2*256+tid]=s;
    }
    for (int idx=tid; idx<320; idx+=256){
      int ty=idx>>6, c=idx&63; float s=0.f;
      #pragma unroll
      for (int i=0;i<NET;i++) if (gDSTT[i]==ty) s += p.b0[i*64+c];
      p.bs0[idx]=s;
    }
    return;
  }
  if (b == 1) {
    if (tid < 64){
      for (int e2=0; e2<NET; e2++){
        const float* W = p.Wd1 + (long)e2*64*64;
        const float* a = p.ad1 + e2*64;
        float s=0.f;
        #pragma unroll 8
        for (int c=0;c<64;c++) s += W[tid*64+c]*a[c];
        p.wv1[e2*256+tid]=s;
      }
    }
    for (int idx=tid; idx<320; idx+=256){
      int ty=idx>>6, c=idx&63; float s=0.f;
      #pragma unroll
      for (int i=0;i<NET;i++) if (gDSTT[i]==ty) s += p.b1[i*64+c];
      p.bs1[idx]=s;
    }
    return;
  }
  int e2 = ((b-2)*256 + tid)*2;
  if (e2 >= ETOT) return;
  int et = 0;
  #pragma unroll
  for (int i=0;i<NET;i++) if (e2 >= t.ebase[i+1]) et = i+1;
  int e = e2 - t.ebase[et];
  int E = t.ebase[et+1]-t.ebase[et];
  int2 d2 = *(const int2*)(t.ei[et] + E + e);
  atomicAdd(&counts[t.rbase[et] + d2.x], 1);
  atomicAdd(&counts[t.rbase[et] + d2.y], 1);
}

// ---------------- scans ----------------
__global__ __launch_bounds__(256) void k_scan1(ScanTab t, const int* __restrict__ counts,
                                               int* __restrict__ offs, int* __restrict__ partials) {
  __shared__ int sd[256];
  int b = blockIdx.x;
  int et = 0;
  #pragma unroll
  for (int i=0;i<NET;i++) if (b >= t.bbase[i+1]) et = i+1;
  int lb = b - t.bbase[et];
  int n = t.nd[et];
  const int* cin = counts + t.cbase[et];
  int* oo = offs + t.obase[et];
  int tid = threadIdx.x;
  int base = lb*1024 + tid*4;
  int v0 = (base+0<n)?cin[base+0]:0;
  int v1 = (base+1<n)?cin[base+1]:0;
  int v2 = (base+2<n)?cin[base+2]:0;
  int v3 = (base+3<n)?cin[base+3]:0;
  int tsum = v0+v1+v2+v3;
  sd[tid]=tsum; __syncthreads();
  for (int off=1; off<256; off<<=1) {
    int x = (tid>=off)? sd[tid-off] : 0;
    __syncthreads();
    sd[tid] += x;
    __syncthreads();
  }
  int run = sd[tid]-tsum;
  if (tid==255) partials[t.pbase[et]+lb]=sd[255];
  if (base+0<n){ oo[base+0]=run; run+=v0; }
  if (base+1<n){ oo[base+1]=run; run+=v1; }
  if (base+2<n){ oo[base+2]=run; run+=v2; }
  if (base+3<n){ oo[base+3]=run; }
}

__global__ __launch_bounds__(256) void k_scan2(ScanTab t, int* __restrict__ partials) {
  __shared__ int sd[256];
  int et = blockIdx.x;
  int nb = t.bbase[et+1]-t.bbase[et];
  int tid = threadIdx.x;
  int v = (tid<nb)? partials[t.pbase[et]+tid] : 0;
  sd[tid]=v; __syncthreads();
  for (int off=1; off<256; off<<=1) {
    int x=(tid>=off)?sd[tid-off]:0;
    __syncthreads();
    sd[tid]+=x;
    __syncthreads();
  }
  if (tid<nb) partials[t.pbase[et]+tid] = sd[tid]-v;
}

__global__ __launch_bounds__(256) void k_scan3(ScanTab t, int* __restrict__ offs,
                                               const int* __restrict__ partials) {
  int b = blockIdx.x;
  int et=0;
  #pragma unroll
  for (int i=0;i<NET;i++) if (b>=t.bbase[i+1]) et=i+1;
  int lb = b - t.bbase[et];
  int n = t.nd[et];
  int* oo = offs + t.obase[et];
  int add = partials[t.pbase[et]+lb];
  int tid = threadIdx.x;
  int base = lb*1024 + tid*4;
  #pragma unroll
  for (int j=0;j<4;j++) if (base+j<n) oo[base+j]+=add;
  if (lb==0 && tid==0) oo[n] = t.ec[et];
}

// ---------------- gemm body (shared by mega + layer1) ----------------
__device__ __forceinline__ void gemm_block(const GemmArgs& t, int b) {
  __shared__ float sX[64][68];
  __shared__ float sW[64][64];
  __shared__ float sdd[3][64][4];
  const int GB1=79,GB2=158,GB3=237,GB4=269,GB5=301,GB6=1083,GB7=2646,GB8=4990,GB9=5772;
  int et = (b>=GB1)+(b>=GB2)+(b>=GB3)+(b>=GB4)+(b>=GB5)+(b>=GB6)+(b>=GB7)+(b>=GB8)+(b>=GB9);
  const int GBb[NET] = {0,GB1,GB2,GB3,GB4,GB5,GB6,GB7,GB8,GB9};
  const int NSa[NET] = {5000,5000,5000,2000,2000,50000,100000,150000,50000,100000};
  int lb = b - GBb[et];
  int Ns = NSa[et];
  int K = t.K;
  const float* X = t.X[et];
  const float* W = t.Wsrc + (long)et*K*64;
  const float* avec = t.asrc + et*64;
  int sbase = gSB[et];
  unsigned short* HS = t.hs + (long)sbase*64;
  float* score = t.ssrc + sbase;

  int nj = gNJ[et];
  const float* wvA = t.wv + gTG[et][0]*256;
  const float* wvB = t.wv + gTG[et][1]*256;
  const float* wvC = t.wv + gTG[et][2]*256;

  int tid = threadIdx.x;
  int row0 = lb*64;
  int tr = tid>>4, tc = tid&15;
  int drow = tid>>2, dq = tid&3;
  float acc[4][4]={};
  float asd0=0.f, asd1=0.f, asd2=0.f;
  for (int k0=0;k0<K;k0+=64){
    #pragma unroll
    for (int p=0;p<4;p++){
      int r = (tid>>4) + 16*p;
      int c = (tid&15)*4;
      int gr = row0 + r;
      float4 xv = make_float4(0.f,0.f,0.f,0.f);
      if (gr < Ns) xv = *(const float4*)(X + (long)gr*K + k0 + c);
      sX[r][c]=xv.x; sX[r][c+1]=xv.y; sX[r][c+2]=xv.z; sX[r][c+3]=xv.w;
      float4 wv4 = *(const float4*)(W + (long)(k0+r)*64 + c);
      *(float4*)&sW[r][c] = wv4;
    }
    __syncthreads();
    #pragma unroll 8
    for (int k=0;k<64;k++){
      float a0=sX[tr*4+0][k],a1=sX[tr*4+1][k],a2=sX[tr*4+2][k],a3=sX[tr*4+3][k];
      float4 b4 = *(const float4*)&sW[k][tc*4];
      acc[0][0]+=a0*b4.x; acc[0][1]+=a0*b4.y; acc[0][2]+=a0*b4.z; acc[0][3]+=a0*b4.w;
      acc[1][0]+=a1*b4.x; acc[1][1]+=a1*b4.y; acc[1][2]+=a1*b4.z; acc[1][3]+=a1*b4.w;
      acc[2][0]+=a2*b4.x; acc[2][1]+=a2*b4.y; acc[2][2]+=a2*b4.z; acc[2][3]+=a2*b4.w;
      acc[3][0]+=a3*b4.x; acc[3][1]+=a3*b4.y; acc[3][2]+=a3*b4.z; acc[3][3]+=a3*b4.w;
    }
    if (nj) {
      int kb = dq*16;
      #pragma unroll
      for (int kk=0; kk<16; kk++){
        float xv = sX[drow][kb+kk];
        asd0 += xv * wvA[k0+kb+kk];
        asd1 += xv * wvB[k0+kb+kk];
        asd2 += xv * wvC[k0+kb+kk];
      }
    }
    __syncthreads();
  }
  if (nj) {
    sdd[0][drow][dq]=asd0;
    sdd[1][drow][dq]=asd1;
    sdd[2][drow][dq]=asd2;
    __syncthreads();
    if (tid < 64) {
      int r = row0 + tid;
      if (r < Ns) {
        for (int j=0;j<nj;j++) {
          float s = sdd[j][tid][0]+sdd[j][tid][1]+sdd[j][tid][2]+sdd[j][tid][3];
          t.sdst[gRB[gTG[et][j]] + r] = s;
        }
      }
    }
  }
  float a4[4];
  #pragma unroll
  for (int j=0;j<4;j++) a4[j]=avec[tc*4+j];
  #pragma unroll
  for (int i=0;i<4;i++){
    int r = row0 + tr*4 + i;
    if (r < Ns){
      ushort4 o;
      o.x=f2bf(acc[i][0]); o.y=f2bf(acc[i][1]);
      o.z=f2bf(acc[i][2]); o.w=f2bf(acc[i][3]);
      *(ushort4*)(HS + (long)r*64 + tc*4) = o;
    }
    float sc = acc[i][0]*a4[0]+acc[i][1]*a4[1]+acc[i][2]*a4[2]+acc[i][3]*a4[3];
    #pragma unroll
    for (int off=1;off<16;off<<=1) sc += __shfl_xor(sc, off);
    if (tc==0 && r<Ns) score[r]=sc;
  }
}

__global__ __launch_bounds__(256) void k_gemm_all(GemmArgs t) {
  gemm_block(t, blockIdx.x);
}

// ---------------- mega: scatter (2 edges/thread) + layer-0 gemm ----------------
__global__ __launch_bounds__(256) void k_mega0(MegaTab t) {
  long long b = blockIdx.x;
  const long long G = NGEMMB, T = NMEGAB;
  long long lo = (b*G)/T, hi = ((b+1)*G)/T;
  if (hi > lo) {
    gemm_block(t.g, (int)lo);
  } else {
    int sidx = (int)(b - lo);
    int e2 = (sidx*256 + threadIdx.x)*2;
    if (e2 >= ETOT) return;
    int et=0;
    #pragma unroll
    for (int i=0;i<NET;i++) if (e2>=gEB[i+1]) et=i+1;
    int e = e2 - gEB[et];
    int E = gEB[et+1]-gEB[et];
    int2 s2 = *(const int2*)(t.ei[et] + e);
    int2 d2 = *(const int2*)(t.ei[et] + E + e);
    int* curb = t.cursor + gOB[et];
    int* csrb = t.csr + gEB[et];
    int p0 = atomicAdd(&curb[d2.x], 1);
    int p1 = atomicAdd(&curb[d2.y], 1);
    csrb[p0] = s2.x;
    csrb[p1] = s2.y;
  }
}

// ---------------- fused aggregation (bf16 hs gather, no max pass) ----------------
__global__ __launch_bounds__(256) void k_agg_all(AggTab t) {
  int node = blockIdx.x*4 + (threadIdx.x>>6);
  int lane = threadIdx.x & 63;
  if (node >= NTOT) return;
  int ty = (node>=5000)+(node>=55000)+(node>=155000)+(node>=305000);
  int r = node - gTOFF[ty];
  float outacc = 0.f;
  int ne = gNIN[ty];
  for (int ii=0; ii<ne; ii++) {
    int et = gINET[ty][ii];
    float sd = t.sdst[gRB[et] + r];
    int ob = gOB[et];
    int beg = t.offs[ob + r];
    int end = t.offs[ob + r + 1];
    if (beg >= end) continue;
    const int* cs = t.csr + gEB[et];
    int sb = gSB[et];
    const float* ss = t.ssrc + sb;
    const unsigned short* hsb = t.hs + (long)sb*64;
    float den=0.f, acc=0.f;
    int e = beg;
    for (; e+8<=end; e+=8){
      int s0=cs[e+0], s1=cs[e+1], s2=cs[e+2], s3=cs[e+3];
      int s4=cs[e+4], s5=cs[e+5], s6=cs[e+6], s7=cs[e+7];
      float l0=ss[s0]+sd; l0=(l0>0.f)?l0:0.2f*l0;
      float l1=ss[s1]+sd; l1=(l1>0.f)?l1:0.2f*l1;
      float l2=ss[s2]+sd; l2=(l2>0.f)?l2:0.2f*l2;
      float l3=ss[s3]+sd; l3=(l3>0.f)?l3:0.2f*l3;
      float l4=ss[s4]+sd; l4=(l4>0.f)?l4:0.2f*l4;
      float l5=ss[s5]+sd; l5=(l5>0.f)?l5:0.2f*l5;
      float l6=ss[s6]+sd; l6=(l6>0.f)?l6:0.2f*l6;
      float l7=ss[s7]+sd; l7=(l7>0.f)?l7:0.2f*l7;
      float x0=__expf(l0), x1=__expf(l1), x2=__expf(l2), x3=__expf(l3);
      float x4=__expf(l4), x5=__expf(l5), x6=__expf(l6), x7=__expf(l7);
      float h0=bf2f(hsb[(long)s0*64+lane]);
      float h1=bf2f(hsb[(long)s1*64+lane]);
      float h2=bf2f(hsb[(long)s2*64+lane]);
      float h3=bf2f(hsb[(long)s3*64+lane]);
      float h4=bf2f(hsb[(long)s4*64+lane]);
      float h5=bf2f(hsb[(long)s5*64+lane]);
      float h6=bf2f(hsb[(long)s6*64+lane]);
      float h7=bf2f(hsb[(long)s7*64+lane]);
      den += ((x0+x1)+(x2+x3)) + ((x4+x5)+(x6+x7));
      acc += x0*h0 + x1*h1 + x2*h2 + x3*h3;
      acc += x4*h4 + x5*h5 + x6*h6 + x7*h7;
    }
    for (; e+4<=end; e+=4){
      int s0=cs[e+0], s1=cs[e+1], s2=cs[e+2], s3=cs[e+3];
      float l0=ss[s0]+sd; l0=(l0>0.f)?l0:0.2f*l0;
      float l1=ss[s1]+sd; l1=(l1>0.f)?l1:0.2f*l1;
      float l2=ss[s2]+sd; l2=(l2>0.f)?l2:0.2f*l2;
      float l3=ss[s3]+sd; l3=(l3>0.f)?l3:0.2f*l3;
      float x0=__expf(l0), x1=__expf(l1), x2=__expf(l2), x3=__expf(l3);
      float h0=bf2f(hsb[(long)s0*64+lane]);
      float h1=bf2f(hsb[(long)s1*64+lane]);
      float h2=bf2f(hsb[(long)s2*64+lane]);
      float h3=bf2f(hsb[(long)s3*64+lane]);
      den += (x0+x1)+(x2+x3);
      acc += x0*h0 + x1*h1 + x2*h2 + x3*h3;
    }
    for (; e<end; e++){
      int s = cs[e];
      float l = ss[s]+sd; l=(l>0.f)?l:0.2f*l;
      float ex = __expf(l);
      den += ex;
      acc += ex*bf2f(hsb[(long)s*64+lane]);
    }
    outacc += acc/(den+1e-16f);
  }
  float o = outacc + t.bsum[ty*64+lane];
  t.xout[(long)node*64+lane] = fmaxf(o,0.f);
}

// ---------------- pooling + head ----------------
__global__ __launch_bounds__(64) void k_pool(PoolTab t, float* __restrict__ pooled) {
  int g = blockIdx.x; int ty = blockIdx.y; int lane = threadIdx.x;
  const int* batch = t.batch[ty];
  int n = t.nt[ty];
  int lo=0, hi=0;
  if (lane==0){
    int a=0,b2=n;
    while(a<b2){int mm=(a+b2)>>1; if (batch[mm]<g) a=mm+1; else b2=mm;}
    lo=a;
    a=lo; b2=n;
    while(a<b2){int mm=(a+b2)>>1; if (batch[mm]<g+1) a=mm+1; else b2=mm;}
    hi=a;
  }
  lo=__shfl(lo,0); hi=__shfl(hi,0);
  const float* x = t.x[ty];
  float acc=0.f;
  for (int i=lo;i<hi;i++) acc += x[(long)i*64+lane];
  int cnt = hi-lo;
  pooled[(long)g*320 + ty*64 + lane] = acc / (float)(cnt>0?cnt:1);
}

__global__ __launch_bounds__(256) void k_final(
    const float* __restrict__ pooled, const float* __restrict__ post,
    const float* __restrict__ Wlin, const float* __restrict__ blin,
    float* __restrict__ out)
{
  int w = (blockIdx.x*256+threadIdx.x)>>6;
  int lane = threadIdx.x&63;
  if (w>=GDIM) return;
  float a0=0.f,a1=0.f;
  for (int k=lane;k<320+PDIM;k+=64){
    float v = (k<320) ? pooled[(long)w*320+k] : post[(long)w*PDIM + (k-320)];
    a0 += v*Wlin[k*2];
    a1 += v*Wlin[k*2+1];
  }
  #pragma unroll
  for (int off=32;off;off>>=1){ a0+=__shfl_xor(a0,off); a1+=__shfl_xor(a1,off); }
  if (lane==0){
    float z0=a0+blin[0], z1=a1+blin[1];
    z0=fmaxf(z0,0.f); z1=fmaxf(z1,0.f);
    float mm=fmaxf(z0,z1);
    float e0=__expf(z0-mm), e1=__expf(z1-mm);
    float inv = 1.f/(e0+e1);
    out[w*2+0]=e0*inv; out[w*2+1]=e1*inv;
  }
}

extern "C" void kernel_launch(void* const* d_in, const int* in_sizes, int n_in,
                              void* d_out, int out_size, void* d_ws, size_t ws_size,
                              hipStream_t stream) {
  (void)in_sizes; (void)n_in; (void)out_size; (void)ws_size;
  char* ws = (char*)d_ws;
  size_t off = 0;
  auto A = [&](size_t nbytes){ size_t o=off; off=(off+nbytes+255)&~((size_t)255); return o; };
  size_t xbuf1_o = A((size_t)NTOT*64*4);
  size_t xbuf2_o = A((size_t)NTOT*64*4);
  size_t hs_o    = A((size_t)469000*64*2);      // bf16 now: 60 MB
  size_t csr_o   = A((size_t)ETOT*4);
  size_t offs_o  = A((size_t)469010*4);
  size_t cur_o   = A((size_t)469010*4);
  size_t cnt_o   = A((size_t)469000*4);
  size_t ssrc_o  = A((size_t)469000*4);
  size_t sdst_o  = A((size_t)469000*4);
  size_t pool_o  = A((size_t)GDIM*320*4);
  size_t wv0_o   = A((size_t)NET*256*4);
  size_t wv1_o   = A((size_t)NET*256*4);
  size_t bs0_o   = A((size_t)320*4);
  size_t bs1_o   = A((size_t)320*4);
  size_t part_o  = A((size_t)460*4);

  float* xbuf1 = (float*)(ws + xbuf1_o);
  float* xbuf2 = (float*)(ws + xbuf2_o);
  unsigned short* hsB = (unsigned short*)(ws + hs_o);
  int*   csr   = (int*)(ws + csr_o);
  int*   offs  = (int*)(ws + offs_o);
  int*   cur   = (int*)(ws + cur_o);
  int*   cnts  = (int*)(ws + cnt_o);
  float* ssrcB = (float*)(ws + ssrc_o);
  float* sdstA = (float*)(ws + sdst_o);
  float* pooled= (float*)(ws + pool_o);
  float* wv0   = (float*)(ws + wv0_o);
  float* wv1   = (float*)(ws + wv1_o);
  float* bs0   = (float*)(ws + bs0_o);
  float* bs1   = (float*)(ws + bs1_o);
  int*   parts = (int*)(ws + part_o);

  int kOB[NET];
  for (int i=0;i<NET;i++) kOB[i] = kRB[i] + i;

  EdgeTab et;
  for (int i=0;i<NET;i++) et.ei[i] = (const int*)d_in[6+i];
  for (int i=0;i<=NET;i++) { et.ebase[i]=kEB[i]; et.rbase[i]=kRB[i]; }
  for (int i=0;i<NET;i++) et.obase[i]=kOB[i];

  ScanTab st;
  for (int i=0;i<=NET;i++) st.bbase[i]=kBB[i];
  for (int i=0;i<NET;i++) { st.cbase[i]=kRB[i]; st.obase[i]=kOB[i]; st.pbase[i]=kBB[i]; st.nd[i]=kND[i]; st.ec[i]=kEC[i]; }

  PrepTab pp;
  pp.Wd0 = (const float*)d_in[22]; pp.ad0 = (const float*)d_in[24]; pp.b0 = (const float*)d_in[25];
  pp.Wd1 = (const float*)d_in[27]; pp.ad1 = (const float*)d_in[29]; pp.b1 = (const float*)d_in[30];
  pp.wv0 = wv0; pp.wv1 = wv1; pp.bs0 = bs0; pp.bs1 = bs1;

  hipMemsetAsync(cnts, 0, (size_t)469000*4, stream);
  k_histprep<<<2+NSCATB,256,0,stream>>>(et, cnts, pp);
  k_scan1<<<kBB[NET],256,0,stream>>>(st, cnts, offs, parts);
  k_scan2<<<NET,256,0,stream>>>(st, parts);
  k_scan3<<<kBB[NET],256,0,stream>>>(st, offs, parts);
  hipMemcpyAsync(cur, offs, (size_t)469010*4, hipMemcpyDeviceToDevice, stream);

  // ---- mega: scatter + layer-0 gemm ----
  MegaTab mt;
  for (int e=0;e<NET;e++) mt.g.X[e] = (const float*)d_in[kSRCT[e]];
  mt.g.Wsrc = (const float*)d_in[21];
  mt.g.asrc = (const float*)d_in[23];
  mt.g.wv = wv0; mt.g.hs = hsB; mt.g.ssrc = ssrcB; mt.g.sdst = sdstA; mt.g.K = 256;
  for (int i=0;i<NET;i++) mt.ei[i] = (const int*)d_in[6+i];
  mt.cursor = cur; mt.csr = csr;
  k_mega0<<<NMEGAB,256,0,stream>>>(mt);

  // ---- layer-0 agg ----
  AggTab a0;
  a0.offs = offs; a0.csr = csr; a0.hs = hsB; a0.ssrc = ssrcB;
  a0.sdst = sdstA; a0.bsum = bs0; a0.xout = xbuf1;
  k_agg_all<<<(NTOT+3)/4,256,0,stream>>>(a0);

  // ---- layer-1 gemm ----
  GemmArgs g1;
  for (int e=0;e<NET;e++) g1.X[e] = (const float*)(xbuf1 + (long)kTOFF[kSRCT[e]]*64);
  g1.Wsrc = (const float*)d_in[26];
  g1.asrc = (const float*)d_in[28];
  g1.wv = wv1; g1.hs = hsB; g1.ssrc = ssrcB; g1.sdst = sdstA; g1.K = 64;
  k_gemm_all<<<NGEMMB,256,0,stream>>>(g1);

  // ---- layer-1 agg ----
  AggTab a1;
  a1.offs = offs; a1.csr = csr; a1.hs = hsB; a1.ssrc = ssrcB;
  a1.sdst = sdstA; a1.bsum = bs1; a1.xout = xbuf2;
  k_agg_all<<<(NTOT+3)/4,256,0,stream>>>(a1);

  // ---- pooling + head ----
  PoolTab pt;
  for (int t=0;t<NTY;t++){
    pt.batch[t] = (const int*)d_in[16+t];
    pt.x[t] = (const float*)(xbuf2 + (long)kTOFF[t]*64);
    pt.nt[t] = kNT[t];
  }
  dim3 pgrid(GDIM, NTY);
  k_pool<<<pgrid,64,0,stream>>>(pt, pooled);

  k_final<<<GDIM/4,256,0,stream>>>(pooled, (const float*)d_in[5],
                                   (const float*)d_in[31], (const float*)d_in[32],
                                   (float*)d_out);
}

// Round 6
// 1580.861 us; speedup vs baseline: 1.9635x; 1.0278x over previous
//
#include <hip/hip_runtime.h>
#include <math.h>

#define NTY 5
#define NET 10
#define NTOT 307000
#define ETOT 6800000
#define GDIM 1024
#define PDIM 768
#define NGEMMB 7335
#define NSCATB 6641             /* 4 edges/thread */
#define NMEGAB (NGEMMB + NSCATB)
#define NHIST_OFF 802           /* 2 prep + 640 Wt0 + 160 Wt1 */

using short8 = __attribute__((ext_vector_type(8))) short;
using f32x4  = __attribute__((ext_vector_type(4))) float;

// ---- compile-time problem tables (host) ----
static const int kSRCT[NET]= {0,0,0,4,4,1,2,3,1,2};
static const int kNT[NTY]  = {5000,50000,100000,150000,2000};
static const int kTOFF[NTY]= {0,5000,55000,155000,305000};
static const int kEB[NET+1]= {0,500000,1500000,2500000,2800000,3400000,3900000,4900000,5900000,6200000,6800000};
static const int kRB[NET+1]= {0,50000,150000,300000,350000,450000,455000,460000,465000,467000,469000};
static const int kBB[NET+1]= {0,49,147,294,343,441,446,451,456,458,460};
static const int kND[NET]  = {50000,100000,150000,50000,100000,5000,5000,5000,2000,2000};
static const int kEC[NET]  = {500000,1000000,1000000,300000,600000,500000,1000000,1000000,300000,600000};

// ---- device tables ----
__device__ const int gOB[NET]   = {0,50001,150002,300003,350004,450005,455006,460007,465008,467009};
__device__ const int gEB[NET+1] = {0,500000,1500000,2500000,2800000,3400000,3900000,4900000,5900000,6200000,6800000};
__device__ const int gSB[NET]   = {0,5000,10000,15000,17000,19000,69000,169000,319000,369000};
__device__ const int gRB[NET]   = {0,50000,150000,300000,350000,450000,455000,460000,465000,467000};
__device__ const int gTOFF[NTY] = {0,5000,55000,155000,305000};
__device__ const int gNIN[NTY]  = {3,2,2,1,2};
__device__ const int gINET[NTY][3] = {{5,6,7},{0,3,0},{1,4,0},{2,0,0},{8,9,0}};
__device__ const int gNJ[NET]   = {3,0,0,2,0,2,2,1,0,0};
__device__ const int gTG[NET][3]= {{5,6,7},{0,0,0},{0,0,0},{8,9,0},{0,0,0},{0,3,0},{1,4,0},{2,0,0},{0,0,0},{0,0,0}};
__device__ const int gDSTT[NET] = {1,2,3,1,2,0,0,0,4,4};

__device__ __forceinline__ unsigned short f2bf(float f){
  unsigned int u = __float_as_uint(f);
  u += 0x7fffu + ((u>>16)&1u);
  return (unsigned short)(u>>16);
}
__device__ __forceinline__ float bf2f(unsigned short h){
  return __uint_as_float(((unsigned int)h)<<16);
}

struct EdgeTab {
  const int* ei[NET];
  int ebase[NET+1];
  int obase[NET];
  int rbase[NET+1];
};
struct ScanTab {
  int bbase[NET+1];
  int cbase[NET];
  int obase[NET];
  int pbase[NET];
  int nd[NET];
  int ec[NET];
};
struct PrepTab {
  const float* Wd0; const float* ad0; const float* b0;
  const float* Wd1; const float* ad1; const float* b1;
  const float* Ws0; const float* Ws1;
  float* wv0; float* wv1; float* bs0; float* bs1;
  unsigned short* Wt0; unsigned short* Wt1;
};
struct PoolTab { const int* batch[NTY]; const float* x[NTY]; int nt[NTY]; };
struct GemmArgs {
  const float* X[NET];
  const unsigned short* Wt;      // [et][col(64)][K] bf16
  const float* asrc;
  const float* wv;
  unsigned short* hs;            // bf16
  float* ssrc;
  float* sdst;
  int K;
};
struct MegaTab {
  GemmArgs g;
  const int* ei[NET];
  int* cursor;
  int* csr;
};
struct AggTab {
  const int* offs;
  const int* csr;
  const unsigned short* hs;      // bf16
  const float* ssrc;
  const float* sdst;
  const float* bsum;
  float* xout;
};

// ---------------- hist (4 edges/thread) + weight-prep + W transpose ----------------
__global__ __launch_bounds__(256) void k_histprep(EdgeTab t, int* __restrict__ counts, PrepTab p) {
  int b = blockIdx.x;
  int tid = threadIdx.x;
  if (b == 0) {
    for (int e2=0; e2<NET; e2++){
      const float* W = p.Wd0 + (long)e2*256*64;
      const float* a = p.ad0 + e2*64;
      float s=0.f;
      #pragma unroll 8
      for (int c=0;c<64;c++) s += W[tid*64+c]*a[c];
      p.wv0[e2*256+tid]=s;
    }
    for (int idx=tid; idx<320; idx+=256){
      int ty=idx>>6, c=idx&63; float s=0.f;
      #pragma unroll
      for (int i=0;i<NET;i++) if (gDSTT[i]==ty) s += p.b0[i*64+c];
      p.bs0[idx]=s;
    }
    return;
  }
  if (b == 1) {
    if (tid < 64){
      for (int e2=0; e2<NET; e2++){
        const float* W = p.Wd1 + (long)e2*64*64;
        const float* a = p.ad1 + e2*64;
        float s=0.f;
        #pragma unroll 8
        for (int c=0;c<64;c++) s += W[tid*64+c]*a[c];
        p.wv1[e2*256+tid]=s;
      }
    }
    for (int idx=tid; idx<320; idx+=256){
      int ty=idx>>6, c=idx&63; float s=0.f;
      #pragma unroll
      for (int i=0;i<NET;i++) if (gDSTT[i]==ty) s += p.b1[i*64+c];
      p.bs1[idx]=s;
    }
    return;
  }
  if (b < 2+640) {            // layer0 W transpose: Wt0[et][col][256]
    int i = b-2;
    int et = i>>6, chunk = i&63;
    int idx = chunk*256 + tid;          // col*256 + k
    int col = idx>>8, k = idx&255;
    p.Wt0[(long)et*16384 + idx] = f2bf(p.Ws0[(long)et*16384 + k*64 + col]);
    return;
  }
  if (b < NHIST_OFF) {        // layer1 W transpose: Wt1[et][col][64]
    int i = b-642;
    int et = i>>4, chunk = i&15;
    int idx = chunk*256 + tid;          // col*64 + k
    int col = idx>>6, k = idx&63;
    p.Wt1[(long)et*4096 + idx] = f2bf(p.Ws1[(long)et*4096 + k*64 + col]);
    return;
  }
  int e4 = ((b-NHIST_OFF)*256 + tid)*4;
  if (e4 >= ETOT) return;
  int et = 0;
  #pragma unroll
  for (int i=0;i<NET;i++) if (e4 >= t.ebase[i+1]) et = i+1;
  int e = e4 - t.ebase[et];
  int E = t.ebase[et+1]-t.ebase[et];
  int4 d4 = *(const int4*)(t.ei[et] + E + e);
  int* cb = counts + t.rbase[et];
  atomicAdd(&cb[d4.x], 1);
  atomicAdd(&cb[d4.y], 1);
  atomicAdd(&cb[d4.z], 1);
  atomicAdd(&cb[d4.w], 1);
}

// ---------------- scans ----------------
__global__ __launch_bounds__(256) void k_scan1(ScanTab t, const int* __restrict__ counts,
                                               int* __restrict__ offs, int* __restrict__ partials) {
  __shared__ int sd[256];
  int b = blockIdx.x;
  int et = 0;
  #pragma unroll
  for (int i=0;i<NET;i++) if (b >= t.bbase[i+1]) et = i+1;
  int lb = b - t.bbase[et];
  int n = t.nd[et];
  const int* cin = counts + t.cbase[et];
  int* oo = offs + t.obase[et];
  int tid = threadIdx.x;
  int base = lb*1024 + tid*4;
  int v0 = (base+0<n)?cin[base+0]:0;
  int v1 = (base+1<n)?cin[base+1]:0;
  int v2 = (base+2<n)?cin[base+2]:0;
  int v3 = (base+3<n)?cin[base+3]:0;
  int tsum = v0+v1+v2+v3;
  sd[tid]=tsum; __syncthreads();
  for (int off=1; off<256; off<<=1) {
    int x = (tid>=off)? sd[tid-off] : 0;
    __syncthreads();
    sd[tid] += x;
    __syncthreads();
  }
  int run = sd[tid]-tsum;
  if (tid==255) partials[t.pbase[et]+lb]=sd[255];
  if (base+0<n){ oo[base+0]=run; run+=v0; }
  if (base+1<n){ oo[base+1]=run; run+=v1; }
  if (base+2<n){ oo[base+2]=run; run+=v2; }
  if (base+3<n){ oo[base+3]=run; }
}

__global__ __launch_bounds__(256) void k_scan2(ScanTab t, int* __restrict__ partials) {
  __shared__ int sd[256];
  int et = blockIdx.x;
  int nb = t.bbase[et+1]-t.bbase[et];
  int tid = threadIdx.x;
  int v = (tid<nb)? partials[t.pbase[et]+tid] : 0;
  sd[tid]=v; __syncthreads();
  for (int off=1; off<256; off<<=1) {
    int x=(tid>=off)?sd[tid-off]:0;
    __syncthreads();
    sd[tid]+=x;
    __syncthreads();
  }
  if (tid<nb) partials[t.pbase[et]+tid] = sd[tid]-v;
}

__global__ __launch_bounds__(256) void k_scan3(ScanTab t, int* __restrict__ offs,
                                               const int* __restrict__ partials) {
  int b = blockIdx.x;
  int et=0;
  #pragma unroll
  for (int i=0;i<NET;i++) if (b>=t.bbase[i+1]) et=i+1;
  int lb = b - t.bbase[et];
  int n = t.nd[et];
  int* oo = offs + t.obase[et];
  int add = partials[t.pbase[et]+lb];
  int tid = threadIdx.x;
  int base = lb*1024 + tid*4;
  #pragma unroll
  for (int j=0;j<4;j++) if (base+j<n) oo[base+j]+=add;
  if (lb==0 && tid==0) oo[n] = t.ec[et];
}

// ---------------- MFMA gemm body ----------------
__device__ __forceinline__ void gemm_block(const GemmArgs& t, int b) {
  __shared__ unsigned short sX[64][72];   // bf16, row-major [row][k], pad 8 (144B rows)
  __shared__ unsigned short sWt[64][72];  // bf16, [col][k]
  __shared__ float sdd[3][64][4];
  const int GB1=79,GB2=158,GB3=237,GB4=269,GB5=301,GB6=1083,GB7=2646,GB8=4990,GB9=5772;
  int et = (b>=GB1)+(b>=GB2)+(b>=GB3)+(b>=GB4)+(b>=GB5)+(b>=GB6)+(b>=GB7)+(b>=GB8)+(b>=GB9);
  const int GBb[NET] = {0,GB1,GB2,GB3,GB4,GB5,GB6,GB7,GB8,GB9};
  const int NSa[NET] = {5000,5000,5000,2000,2000,50000,100000,150000,50000,100000};
  int lb = b - GBb[et];
  int Ns = NSa[et];
  int K = t.K;
  const float* X = t.X[et];
  const unsigned short* Wt = t.Wt + (long)et*64*K;
  const float* avec = t.asrc + et*64;
  int sbase = gSB[et];
  unsigned short* HS = t.hs + (long)sbase*64;
  float* score = t.ssrc + sbase;

  int nj = gNJ[et];
  const float* wvA = t.wv + gTG[et][0]*256;
  const float* wvB = t.wv + gTG[et][1]*256;
  const float* wvC = t.wv + gTG[et][2]*256;

  int tid = threadIdx.x;
  int w = tid>>6, lane = tid&63;
  int row0 = lb*64;
  int l15 = lane&15, lg = lane>>4;
  int arow = w*16 + l15;
  int kgrp = lg*8;
  int drow = tid>>2, dq = tid&3;
  f32x4 acc0={0.f,0.f,0.f,0.f}, acc1={0.f,0.f,0.f,0.f}, acc2={0.f,0.f,0.f,0.f}, acc3={0.f,0.f,0.f,0.f};
  float asd0=0.f, asd1=0.f, asd2=0.f;

  for (int k0=0;k0<K;k0+=64){
    // stage X (fp32 -> bf16), coalesced
    #pragma unroll
    for (int p=0;p<4;p++){
      int r = (tid>>4) + 16*p;
      int c = (tid&15)*4;
      int gr = row0 + r;
      float4 xv = make_float4(0.f,0.f,0.f,0.f);
      if (gr < Ns) xv = *(const float4*)(X + (long)gr*K + k0 + c);
      ushort4 o; o.x=f2bf(xv.x); o.y=f2bf(xv.y); o.z=f2bf(xv.z); o.w=f2bf(xv.w);
      *(ushort4*)&sX[r][c] = o;
    }
    // stage Wt (bf16 [col][K] global -> [col][k] LDS)
    {
      int cq = tid>>2, kq = tid&3;
      const unsigned short* ws = Wt + (long)cq*K + k0;
      #pragma unroll
      for (int it=0; it<4; it++){
        int k = kq*4 + it*16;
        *(ushort4*)&sWt[cq][k] = *(const ushort4*)(ws + k);
      }
    }
    __syncthreads();
    #pragma unroll
    for (int ks=0; ks<64; ks+=32){
      short8 af = *(const short8*)&sX[arow][ks+kgrp];
      short8 b0 = *(const short8*)&sWt[ 0+l15][ks+kgrp];
      short8 b1 = *(const short8*)&sWt[16+l15][ks+kgrp];
      short8 b2 = *(const short8*)&sWt[32+l15][ks+kgrp];
      short8 b3 = *(const short8*)&sWt[48+l15][ks+kgrp];
      acc0 = __builtin_amdgcn_mfma_f32_16x16x32_bf16(af, b0, acc0, 0, 0, 0);
      acc1 = __builtin_amdgcn_mfma_f32_16x16x32_bf16(af, b1, acc1, 0, 0, 0);
      acc2 = __builtin_amdgcn_mfma_f32_16x16x32_bf16(af, b2, acc2, 0, 0, 0);
      acc3 = __builtin_amdgcn_mfma_f32_16x16x32_bf16(af, b3, acc3, 0, 0, 0);
    }
    if (nj) {
      int kb = dq*16;
      #pragma unroll
      for (int kk=0; kk<16; kk++){
        float xv = bf2f(sX[drow][kb+kk]);
        asd0 += xv * wvA[k0+kb+kk];
        asd1 += xv * wvB[k0+kb+kk];
        asd2 += xv * wvC[k0+kb+kk];
      }
    }
    __syncthreads();
  }
  if (nj) {
    sdd[0][drow][dq]=asd0;
    sdd[1][drow][dq]=asd1;
    sdd[2][drow][dq]=asd2;
    __syncthreads();
    if (tid < 64) {
      int r = row0 + tid;
      if (r < Ns) {
        for (int j=0;j<nj;j++) {
          float s = sdd[j][tid][0]+sdd[j][tid][1]+sdd[j][tid][2]+sdd[j][tid][3];
          t.sdst[gRB[gTG[et][j]] + r] = s;
        }
      }
    }
  }
  // epilogue: C/D layout col=lane&15, row=(lane>>4)*4+reg  [guide-verified]
  float av0 = avec[ 0+l15], av1 = avec[16+l15], av2 = avec[32+l15], av3 = avec[48+l15];
  int growb = row0 + w*16 + lg*4;
  #pragma unroll
  for (int r=0;r<4;r++){
    int grow = growb + r;
    if (grow < Ns){
      HS[(long)grow*64 +  0+l15] = f2bf(acc0[r]);
      HS[(long)grow*64 + 16+l15] = f2bf(acc1[r]);
      HS[(long)grow*64 + 32+l15] = f2bf(acc2[r]);
      HS[(long)grow*64 + 48+l15] = f2bf(acc3[r]);
    }
    float s = acc0[r]*av0 + acc1[r]*av1 + acc2[r]*av2 + acc3[r]*av3;
    s += __shfl_xor(s, 1);
    s += __shfl_xor(s, 2);
    s += __shfl_xor(s, 4);
    s += __shfl_xor(s, 8);
    if (l15==0 && grow<Ns) score[grow]=s;
  }
}

__global__ __launch_bounds__(256) void k_gemm_all(GemmArgs t) {
  gemm_block(t, blockIdx.x);
}

// ---------------- mega: scatter (4 edges/thread) + layer-0 gemm ----------------
__global__ __launch_bounds__(256) void k_mega0(MegaTab t) {
  long long b = blockIdx.x;
  const long long G = NGEMMB, T = NMEGAB;
  long long lo = (b*G)/T, hi = ((b+1)*G)/T;
  if (hi > lo) {
    gemm_block(t.g, (int)lo);
  } else {
    int sidx = (int)(b - lo);
    int e4 = (sidx*256 + threadIdx.x)*4;
    if (e4 >= ETOT) return;
    int et=0;
    #pragma unroll
    for (int i=0;i<NET;i++) if (e4>=gEB[i+1]) et=i+1;
    int e = e4 - gEB[et];
    int E = gEB[et+1]-gEB[et];
    int4 s4 = *(const int4*)(t.ei[et] + e);
    int4 d4 = *(const int4*)(t.ei[et] + E + e);
    int* curb = t.cursor + gOB[et];
    int* csrb = t.csr + gEB[et];
    int p0 = atomicAdd(&curb[d4.x], 1);
    int p1 = atomicAdd(&curb[d4.y], 1);
    int p2 = atomicAdd(&curb[d4.z], 1);
    int p3 = atomicAdd(&curb[d4.w], 1);
    csrb[p0] = s4.x;
    csrb[p1] = s4.y;
    csrb[p2] = s4.z;
    csrb[p3] = s4.w;
  }
}

// ---------------- fused aggregation (bf16 hs gather, no max pass) ----------------
__global__ __launch_bounds__(256) void k_agg_all(AggTab t) {
  int node = blockIdx.x*4 + (threadIdx.x>>6);
  int lane = threadIdx.x & 63;
  if (node >= NTOT) return;
  int ty = (node>=5000)+(node>=55000)+(node>=155000)+(node>=305000);
  int r = node - gTOFF[ty];
  float outacc = 0.f;
  int ne = gNIN[ty];
  for (int ii=0; ii<ne; ii++) {
    int et = gINET[ty][ii];
    float sd = t.sdst[gRB[et] + r];
    int ob = gOB[et];
    int beg = t.offs[ob + r];
    int end = t.offs[ob + r + 1];
    if (beg >= end) continue;
    const int* cs = t.csr + gEB[et];
    int sb = gSB[et];
    const float* ss = t.ssrc + sb;
    const unsigned short* hsb = t.hs + (long)sb*64;
    float den=0.f, acc=0.f;
    int e = beg;
    for (; e+8<=end; e+=8){
      int s0=cs[e+0], s1=cs[e+1], s2=cs[e+2], s3=cs[e+3];
      int s4=cs[e+4], s5=cs[e+5], s6=cs[e+6], s7=cs[e+7];
      float l0=ss[s0]+sd; l0=(l0>0.f)?l0:0.2f*l0;
      float l1=ss[s1]+sd; l1=(l1>0.f)?l1:0.2f*l1;
      float l2=ss[s2]+sd; l2=(l2>0.f)?l2:0.2f*l2;
      float l3=ss[s3]+sd; l3=(l3>0.f)?l3:0.2f*l3;
      float l4=ss[s4]+sd; l4=(l4>0.f)?l4:0.2f*l4;
      float l5=ss[s5]+sd; l5=(l5>0.f)?l5:0.2f*l5;
      float l6=ss[s6]+sd; l6=(l6>0.f)?l6:0.2f*l6;
      float l7=ss[s7]+sd; l7=(l7>0.f)?l7:0.2f*l7;
      float x0=__expf(l0), x1=__expf(l1), x2=__expf(l2), x3=__expf(l3);
      float x4=__expf(l4), x5=__expf(l5), x6=__expf(l6), x7=__expf(l7);
      float h0=bf2f(hsb[(long)s0*64+lane]);
      float h1=bf2f(hsb[(long)s1*64+lane]);
      float h2=bf2f(hsb[(long)s2*64+lane]);
      float h3=bf2f(hsb[(long)s3*64+lane]);
      float h4=bf2f(hsb[(long)s4*64+lane]);
      float h5=bf2f(hsb[(long)s5*64+lane]);
      float h6=bf2f(hsb[(long)s6*64+lane]);
      float h7=bf2f(hsb[(long)s7*64+lane]);
      den += ((x0+x1)+(x2+x3)) + ((x4+x5)+(x6+x7));
      acc += x0*h0 + x1*h1 + x2*h2 + x3*h3;
      acc += x4*h4 + x5*h5 + x6*h6 + x7*h7;
    }
    for (; e+4<=end; e+=4){
      int s0=cs[e+0], s1=cs[e+1], s2=cs[e+2], s3=cs[e+3];
      float l0=ss[s0]+sd; l0=(l0>0.f)?l0:0.2f*l0;
      float l1=ss[s1]+sd; l1=(l1>0.f)?l1:0.2f*l1;
      float l2=ss[s2]+sd; l2=(l2>0.f)?l2:0.2f*l2;
      float l3=ss[s3]+sd; l3=(l3>0.f)?l3:0.2f*l3;
      float x0=__expf(l0), x1=__expf(l1), x2=__expf(l2), x3=__expf(l3);
      float h0=bf2f(hsb[(long)s0*64+lane]);
      float h1=bf2f(hsb[(long)s1*64+lane]);
      float h2=bf2f(hsb[(long)s2*64+lane]);
      float h3=bf2f(hsb[(long)s3*64+lane]);
      den += (x0+x1)+(x2+x3);
      acc += x0*h0 + x1*h1 + x2*h2 + x3*h3;
    }
    for (; e<end; e++){
      int s = cs[e];
      float l = ss[s]+sd; l=(l>0.f)?l:0.2f*l;
      float ex = __expf(l);
      den += ex;
      acc += ex*bf2f(hsb[(long)s*64+lane]);
    }
    outacc += acc/(den+1e-16f);
  }
  float o = outacc + t.bsum[ty*64+lane];
  t.xout[(long)node*64+lane] = fmaxf(o,0.f);
}

// ---------------- pooling + head ----------------
__global__ __launch_bounds__(64) void k_pool(PoolTab t, float* __restrict__ pooled) {
  int g = blockIdx.x; int ty = blockIdx.y; int lane = threadIdx.x;
  const int* batch = t.batch[ty];
  int n = t.nt[ty];
  int lo=0, hi=0;
  if (lane==0){
    int a=0,b2=n;
    while(a<b2){int mm=(a+b2)>>1; if (batch[mm]<g) a=mm+1; else b2=mm;}
    lo=a;
    a=lo; b2=n;
    while(a<b2){int mm=(a+b2)>>1; if (batch[mm]<g+1) a=mm+1; else b2=mm;}
    hi=a;
  }
  lo=__shfl(lo,0); hi=__shfl(hi,0);
  const float* x = t.x[ty];
  float acc=0.f;
  for (int i=lo;i<hi;i++) acc += x[(long)i*64+lane];
  int cnt = hi-lo;
  pooled[(long)g*320 + ty*64 + lane] = acc / (float)(cnt>0?cnt:1);
}

__global__ __launch_bounds__(256) void k_final(
    const float* __restrict__ pooled, const float* __restrict__ post,
    const float* __restrict__ Wlin, const float* __restrict__ blin,
    float* __restrict__ out)
{
  int w = (blockIdx.x*256+threadIdx.x)>>6;
  int lane = threadIdx.x&63;
  if (w>=GDIM) return;
  float a0=0.f,a1=0.f;
  for (int k=lane;k<320+PDIM;k+=64){
    float v = (k<320) ? pooled[(long)w*320+k] : post[(long)w*PDIM + (k-320)];
    a0 += v*Wlin[k*2];
    a1 += v*Wlin[k*2+1];
  }
  #pragma unroll
  for (int off=32;off;off>>=1){ a0+=__shfl_xor(a0,off); a1+=__shfl_xor(a1,off); }
  if (lane==0){
    float z0=a0+blin[0], z1=a1+blin[1];
    z0=fmaxf(z0,0.f); z1=fmaxf(z1,0.f);
    float mm=fmaxf(z0,z1);
    float e0=__expf(z0-mm), e1=__expf(z1-mm);
    float inv = 1.f/(e0+e1);
    out[w*2+0]=e0*inv; out[w*2+1]=e1*inv;
  }
}

extern "C" void kernel_launch(void* const* d_in, const int* in_sizes, int n_in,
                              void* d_out, int out_size, void* d_ws, size_t ws_size,
                              hipStream_t stream) {
  (void)in_sizes; (void)n_in; (void)out_size; (void)ws_size;
  char* ws = (char*)d_ws;
  size_t off = 0;
  auto A = [&](size_t nbytes){ size_t o=off; off=(off+nbytes+255)&~((size_t)255); return o; };
  size_t xbuf1_o = A((size_t)NTOT*64*4);
  size_t xbuf2_o = A((size_t)NTOT*64*4);
  size_t hs_o    = A((size_t)469000*64*2);
  size_t csr_o   = A((size_t)ETOT*4);
  size_t offs_o  = A((size_t)469010*4);
  size_t cur_o   = A((size_t)469010*4);
  size_t cnt_o   = A((size_t)469000*4);
  size_t ssrc_o  = A((size_t)469000*4);
  size_t sdst_o  = A((size_t)469000*4);
  size_t pool_o  = A((size_t)GDIM*320*4);
  size_t wv0_o   = A((size_t)NET*256*4);
  size_t wv1_o   = A((size_t)NET*256*4);
  size_t bs0_o   = A((size_t)320*4);
  size_t bs1_o   = A((size_t)320*4);
  size_t part_o  = A((size_t)460*4);
  size_t wt0_o   = A((size_t)NET*64*256*2);
  size_t wt1_o   = A((size_t)NET*64*64*2);

  float* xbuf1 = (float*)(ws + xbuf1_o);
  float* xbuf2 = (float*)(ws + xbuf2_o);
  unsigned short* hsB = (unsigned short*)(ws + hs_o);
  int*   csr   = (int*)(ws + csr_o);
  int*   offs  = (int*)(ws + offs_o);
  int*   cur   = (int*)(ws + cur_o);
  int*   cnts  = (int*)(ws + cnt_o);
  float* ssrcB = (float*)(ws + ssrc_o);
  float* sdstA = (float*)(ws + sdst_o);
  float* pooled= (float*)(ws + pool_o);
  float* wv0   = (float*)(ws + wv0_o);
  float* wv1   = (float*)(ws + wv1_o);
  float* bs0   = (float*)(ws + bs0_o);
  float* bs1   = (float*)(ws + bs1_o);
  int*   parts = (int*)(ws + part_o);
  unsigned short* Wt0 = (unsigned short*)(ws + wt0_o);
  unsigned short* Wt1 = (unsigned short*)(ws + wt1_o);

  int kOB[NET];
  for (int i=0;i<NET;i++) kOB[i] = kRB[i] + i;

  EdgeTab et;
  for (int i=0;i<NET;i++) et.ei[i] = (const int*)d_in[6+i];
  for (int i=0;i<=NET;i++) { et.ebase[i]=kEB[i]; et.rbase[i]=kRB[i]; }
  for (int i=0;i<NET;i++) et.obase[i]=kOB[i];

  ScanTab st;
  for (int i=0;i<=NET;i++) st.bbase[i]=kBB[i];
  for (int i=0;i<NET;i++) { st.cbase[i]=kRB[i]; st.obase[i]=kOB[i]; st.pbase[i]=kBB[i]; st.nd[i]=kND[i]; st.ec[i]=kEC[i]; }

  PrepTab pp;
  pp.Wd0 = (const float*)d_in[22]; pp.ad0 = (const float*)d_in[24]; pp.b0 = (const float*)d_in[25];
  pp.Wd1 = (const float*)d_in[27]; pp.ad1 = (const float*)d_in[29]; pp.b1 = (const float*)d_in[30];
  pp.Ws0 = (const float*)d_in[21]; pp.Ws1 = (const float*)d_in[26];
  pp.wv0 = wv0; pp.wv1 = wv1; pp.bs0 = bs0; pp.bs1 = bs1;
  pp.Wt0 = Wt0; pp.Wt1 = Wt1;

  hipMemsetAsync(cnts, 0, (size_t)469000*4, stream);
  k_histprep<<<NHIST_OFF+NSCATB,256,0,stream>>>(et, cnts, pp);
  k_scan1<<<kBB[NET],256,0,stream>>>(st, cnts, offs, parts);
  k_scan2<<<NET,256,0,stream>>>(st, parts);
  k_scan3<<<kBB[NET],256,0,stream>>>(st, offs, parts);
  hipMemcpyAsync(cur, offs, (size_t)469010*4, hipMemcpyDeviceToDevice, stream);

  // ---- mega: scatter + layer-0 gemm ----
  MegaTab mt;
  for (int e=0;e<NET;e++) mt.g.X[e] = (const float*)d_in[kSRCT[e]];
  mt.g.Wt = Wt0;
  mt.g.asrc = (const float*)d_in[23];
  mt.g.wv = wv0; mt.g.hs = hsB; mt.g.ssrc = ssrcB; mt.g.sdst = sdstA; mt.g.K = 256;
  for (int i=0;i<NET;i++) mt.ei[i] = (const int*)d_in[6+i];
  mt.cursor = cur; mt.csr = csr;
  k_mega0<<<NMEGAB,256,0,stream>>>(mt);

  // ---- layer-0 agg ----
  AggTab a0;
  a0.offs = offs; a0.csr = csr; a0.hs = hsB; a0.ssrc = ssrcB;
  a0.sdst = sdstA; a0.bsum = bs0; a0.xout = xbuf1;
  k_agg_all<<<(NTOT+3)/4,256,0,stream>>>(a0);

  // ---- layer-1 gemm ----
  GemmArgs g1;
  for (int e=0;e<NET;e++) g1.X[e] = (const float*)(xbuf1 + (long)kTOFF[kSRCT[e]]*64);
  g1.Wt = Wt1;
  g1.asrc = (const float*)d_in[28];
  g1.wv = wv1; g1.hs = hsB; g1.ssrc = ssrcB; g1.sdst = sdstA; g1.K = 64;
  k_gemm_all<<<NGEMMB,256,0,stream>>>(g1);

  // ---- layer-1 agg ----
  AggTab a1;
  a1.offs = offs; a1.csr = csr; a1.hs = hsB; a1.ssrc = ssrcB;
  a1.sdst = sdstA; a1.bsum = bs1; a1.xout = xbuf2;
  k_agg_all<<<(NTOT+3)/4,256,0,stream>>>(a1);

  // ---- pooling + head ----
  PoolTab pt;
  for (int t=0;t<NTY;t++){
    pt.batch[t] = (const int*)d_in[16+t];
    pt.x[t] = (const float*)(xbuf2 + (long)kTOFF[t]*64);
    pt.nt[t] = kNT[t];
  }
  dim3 pgrid(GDIM, NTY);
  k_pool<<<pgrid,64,0,stream>>>(pt, pooled);

  k_final<<<GDIM/4,256,0,stream>>>(pooled, (const float*)d_in[5],
                                   (const float*)d_in[31], (const float*)d_in[32],
                                   (float*)d_out);
}